// Round 1
// baseline (340.297 us; speedup 1.0000x reference)
//
#include <hip/hip_runtime.h>
#include <hip/hip_bf16.h>
#include <math.h>

typedef __hip_bfloat16 bf16;
typedef short v8s __attribute__((ext_vector_type(8)));
typedef float v4f __attribute__((ext_vector_type(4)));

#define B_TOK 4096
#define E_EXP 8
#define D_IN  768
#define D_H   2048
#define D_OUT 768

// ---------------------------------------------------------------- helpers
__device__ __forceinline__ void gl_lds16(const bf16* g, bf16* l) {
  __builtin_amdgcn_global_load_lds(
      (const __attribute__((address_space(1))) unsigned int*)g,
      (__attribute__((address_space(3))) unsigned int*)l, 16, 0, 0);
}

// ---------------------------------------------------------------- x -> bf16
__global__ void cvt_x_kernel(const float* __restrict__ x, bf16* __restrict__ xb) {
  int i = blockIdx.x * 256 + threadIdx.x;          // 786432 threads, 4 elems each
  float4 v = ((const float4*)x)[i];
  union { bf16 h[4]; uint2 u; } pk;
  pk.h[0] = __float2bfloat16(v.x); pk.h[1] = __float2bfloat16(v.y);
  pk.h[2] = __float2bfloat16(v.z); pk.h[3] = __float2bfloat16(v.w);
  ((uint2*)xb)[i] = pk.u;
}

// ---------------------------------------------- W [E][K][N] f32 -> Wt [E][N][K] bf16
__global__ void transpose_cvt(const float* __restrict__ W, bf16* __restrict__ Wt,
                              int K, int N) {
  __shared__ bf16 tile[64][65];
  int e = blockIdx.z;
  int k0 = blockIdx.y * 64, n0 = blockIdx.x * 64;
  const float* Wp = W + (size_t)e * K * N;
  bf16* Wtp = Wt + (size_t)e * N * K;
  int t = threadIdx.x;
  int cr = t >> 4;            // 0..15
  int cc = (t & 15) * 4;      // col (n) within tile
  #pragma unroll
  for (int p = 0; p < 4; ++p) {
    int kr = cr + p * 16;
    float4 v = *(const float4*)(Wp + (size_t)(k0 + kr) * N + n0 + cc);
    tile[cc + 0][kr] = __float2bfloat16(v.x);
    tile[cc + 1][kr] = __float2bfloat16(v.y);
    tile[cc + 2][kr] = __float2bfloat16(v.z);
    tile[cc + 3][kr] = __float2bfloat16(v.w);
  }
  __syncthreads();
  #pragma unroll
  for (int p = 0; p < 16; ++p) {
    int o = p * 256 + t;       // 0..4095
    int n = o >> 6, k = o & 63;
    Wtp[(size_t)(n0 + n) * K + k0 + k] = tile[n][k];
  }
}

// ---------------------------------------------------------------- gating
__global__ void gate_kernel(const float* __restrict__ x, const float* __restrict__ wg,
                            float* __restrict__ gates, int* __restrict__ tidx,
                            int* __restrict__ counts, float* __restrict__ importance) {
  int gt = blockIdx.x * 256 + threadIdx.x;
  int tok = gt >> 6, l = gt & 63;
  if (tok >= B_TOK) return;
  const float* xr = x + (size_t)tok * D_IN;
  float acc[8] = {0.f,0.f,0.f,0.f,0.f,0.f,0.f,0.f};
  #pragma unroll
  for (int i = 0; i < 12; ++i) {
    int k = l + 64 * i;
    float xv = xr[k];
    const float* wr = wg + (size_t)k * 8;
    float4 w0 = *(const float4*)wr;
    float4 w1 = *(const float4*)(wr + 4);
    acc[0] += xv * w0.x; acc[1] += xv * w0.y; acc[2] += xv * w0.z; acc[3] += xv * w0.w;
    acc[4] += xv * w1.x; acc[5] += xv * w1.y; acc[6] += xv * w1.z; acc[7] += xv * w1.w;
  }
  #pragma unroll
  for (int d = 1; d < 64; d <<= 1)
    #pragma unroll
    for (int e = 0; e < 8; ++e) acc[e] += __shfl_xor(acc[e], d);
  if (l == 0) {
    int i1 = 0; float v1 = acc[0];
    #pragma unroll
    for (int e = 1; e < 8; ++e) if (acc[e] > v1) { v1 = acc[e]; i1 = e; }
    int i2 = -1; float v2 = -1e30f;
    #pragma unroll
    for (int e = 0; e < 8; ++e) if (e != i1 && acc[e] > v2) { v2 = acc[e]; i2 = e; }
    float ex = __expf(v2 - v1);                 // <= 1
    float g1 = 1.f / (1.f + ex), g2 = ex / (1.f + ex);
    gates[2 * tok] = g1; gates[2 * tok + 1] = g2;
    tidx[2 * tok] = i1;  tidx[2 * tok + 1] = i2;
    atomicAdd(&counts[i1], 1); atomicAdd(&counts[i2], 1);
    atomicAdd(&importance[i1], g1); atomicAdd(&importance[i2], g2);
  }
}

// ------------------------------------------------- offsets + aux loss (1 thread)
__global__ void finalize_gate(const int* __restrict__ counts, int* __restrict__ offsets,
                              const float* __restrict__ importance, float* loss_out) {
  if (threadIdx.x != 0) return;
  int off = 0; float im[8], ld[8];
  for (int e = 0; e < 8; ++e) {
    offsets[e] = off; off += counts[e];
    im[e] = importance[e]; ld[e] = (float)counts[e];
  }
  float mi = 0.f, ml = 0.f;
  for (int e = 0; e < 8; ++e) { mi += im[e]; ml += ld[e]; }
  mi *= 0.125f; ml *= 0.125f;
  float vi = 0.f, vl = 0.f;
  for (int e = 0; e < 8; ++e) {
    float d = im[e] - mi; vi += d * d;
    float d2 = ld[e] - ml; vl += d2 * d2;
  }
  vi /= 7.f; vl /= 7.f;
  *loss_out = 0.01f * (vi / (mi * mi + 1e-10f) + vl / (ml * ml + 1e-10f));
}

// ---------------------------------------------------------------- slot assign
__global__ void assign_kernel(const int* __restrict__ tidx, const int* __restrict__ offsets,
                              int* __restrict__ cursor, int* __restrict__ row_ids,
                              int* __restrict__ pos) {
  int t = blockIdx.x * 256 + threadIdx.x;
  if (t >= B_TOK) return;
  #pragma unroll
  for (int s = 0; s < 2; ++s) {
    int e = tidx[2 * t + s];
    int p = atomicAdd(&cursor[e], 1);
    int r = offsets[e] + p;
    row_ids[r] = t;
    pos[2 * t + s] = r;
  }
}

// ---------------------------------------------------------------- grouped GEMM
// C[r][n] = act(sum_k A[r][k] * Wt[e][n][k] + bias[e][n]) -> bf16 Out[r][n]
// m97 structure: 2-barrier K-loop, global_load_lds width 16, XOR-(row&7) chunk swizzle.
template<int KDIM, int BM, bool GATHER, bool GELU>
__global__ __launch_bounds__(256)
void gemm_mlp(const bf16* __restrict__ Ab, const bf16* __restrict__ Wt,
              const float* __restrict__ bias, bf16* __restrict__ Outb,
              const int* __restrict__ row_ids, const int* __restrict__ cnt_off,
              const int N) {
  constexpr int BK = 64;
  constexpr int BN = 128;
  constexpr int ITA = BM / 32;   // global_load_lds per wave for A
  constexpr int FM  = BM / 32;   // 16-row frags per wave in M
  __shared__ __align__(16) bf16 lsA[BM * BK];
  __shared__ __align__(16) bf16 lsB[BN * BK];
  const int e = blockIdx.z;
  const int cnt = cnt_off[e];
  const int rowb = blockIdx.y;
  if (rowb * BM >= cnt) return;
  const int off = cnt_off[8 + e];
  const int colb = blockIdx.x;
  const int t = (int)threadIdx.x, w = t >> 6, l = t & 63;
  const int cs = (l & 7) ^ (l >> 3);         // pre-swizzled source chunk col
  const bf16* gA[ITA];
  const bf16* gB[4];
  #pragma unroll
  for (int it = 0; it < ITA; ++it) {
    int rt = (it * 4 + w) * 8 + (l >> 3);    // tile row; rt&7 == l>>3
    int r = rowb * BM + rt;
    int rc = r < cnt ? r : cnt - 1;
    long arow = GATHER ? (long)row_ids[off + rc] : (long)(off + rc);
    gA[it] = Ab + arow * (long)KDIM + cs * 8;
  }
  #pragma unroll
  for (int it = 0; it < 4; ++it) {
    int rt = (it * 4 + w) * 8 + (l >> 3);
    gB[it] = Wt + ((size_t)e * N + (size_t)colb * BN + rt) * KDIM + cs * 8;
  }
  v4f acc[FM][4] = {};
  const int wm = w >> 1, wn = w & 1;
  for (int ks = 0; ks < KDIM / BK; ++ks) {
    const int k0 = ks * BK;
    #pragma unroll
    for (int it = 0; it < ITA; ++it) gl_lds16(gA[it] + k0, lsA + (it * 4 + w) * 512);
    #pragma unroll
    for (int it = 0; it < 4; ++it)   gl_lds16(gB[it] + k0, lsB + (it * 4 + w) * 512);
    __syncthreads();   // compiler drains vmcnt before barrier
    #pragma unroll
    for (int kk = 0; kk < 2; ++kk) {
      v8s af[FM], bfr[4];
      #pragma unroll
      for (int fm = 0; fm < FM; ++fm) {
        int row = wm * (BM / 2) + fm * 16 + (l & 15);
        int cg = kk * 4 + (l >> 4);
        af[fm] = *(const v8s*)(lsA + row * BK + ((cg ^ (row & 7)) << 3));
      }
      #pragma unroll
      for (int fn = 0; fn < 4; ++fn) {
        int row = wn * 64 + fn * 16 + (l & 15);
        int cg = kk * 4 + (l >> 4);
        bfr[fn] = *(const v8s*)(lsB + row * BK + ((cg ^ (row & 7)) << 3));
      }
      #pragma unroll
      for (int fm = 0; fm < FM; ++fm)
        #pragma unroll
        for (int fn = 0; fn < 4; ++fn)
          acc[fm][fn] = __builtin_amdgcn_mfma_f32_16x16x32_bf16(af[fm], bfr[fn], acc[fm][fn], 0, 0, 0);
    }
    __syncthreads();
  }
  // epilogue: bias (+gelu) -> bf16
  const float* bp = bias + (size_t)e * N + (size_t)colb * BN;
  #pragma unroll
  for (int fm = 0; fm < FM; ++fm) {
    int lr0 = wm * (BM / 2) + fm * 16 + (l >> 4) * 4;
    #pragma unroll
    for (int fn = 0; fn < 4; ++fn) {
      int lcol = wn * 64 + fn * 16 + (l & 15);
      float bv = bp[lcol];
      #pragma unroll
      for (int q = 0; q < 4; ++q) {
        int lr = lr0 + q;
        int r = rowb * BM + lr;
        if (r < cnt) {
          float v = acc[fm][fn][q] + bv;
          if (GELU) {
            float u = 0.7978845608028654f * (v + 0.044715f * v * v * v);
            float th = 1.f - 2.f / (__expf(2.f * u) + 1.f);   // tanh(u)
            v = 0.5f * v * (1.f + th);
          }
          Outb[(size_t)(off + r) * N + (size_t)colb * BN + lcol] = __float2bfloat16(v);
        }
      }
    }
  }
}

// ---------------------------------------------------------------- combine
__global__ void combine_kernel(const bf16* __restrict__ z, const float* __restrict__ gates,
                               const int* __restrict__ pos, float* __restrict__ y) {
  int gt = blockIdx.x * 256 + threadIdx.x;
  int tok = gt >> 6, l = gt & 63;
  if (tok >= B_TOK) return;
  const bf16* z1 = z + (size_t)pos[2 * tok] * D_OUT;
  const bf16* z2 = z + (size_t)pos[2 * tok + 1] * D_OUT;
  float g1 = gates[2 * tok], g2 = gates[2 * tok + 1];
  float a[12], b[12];
  float m1 = -1e30f, m2 = -1e30f;
  #pragma unroll
  for (int i = 0; i < 12; ++i) {
    a[i] = __bfloat162float(z1[l + 64 * i]);
    b[i] = __bfloat162float(z2[l + 64 * i]);
    m1 = fmaxf(m1, a[i]); m2 = fmaxf(m2, b[i]);
  }
  #pragma unroll
  for (int d = 1; d < 64; d <<= 1) {
    m1 = fmaxf(m1, __shfl_xor(m1, d));
    m2 = fmaxf(m2, __shfl_xor(m2, d));
  }
  float s1 = 0.f, s2 = 0.f;
  #pragma unroll
  for (int i = 0; i < 12; ++i) { s1 += __expf(a[i] - m1); s2 += __expf(b[i] - m2); }
  #pragma unroll
  for (int d = 1; d < 64; d <<= 1) { s1 += __shfl_xor(s1, d); s2 += __shfl_xor(s2, d); }
  float c1 = g1 / s1, c2 = g2 / s2;
  #pragma unroll
  for (int i = 0; i < 12; ++i) {
    float cmb = c1 * __expf(a[i] - m1) + c2 * __expf(b[i] - m2);
    y[(size_t)tok * D_OUT + l + 64 * i] = logf(cmb == 0.f ? 2.2204460492503131e-16f : cmb);
  }
}

// ---------------------------------------------------------------- launch
extern "C" void kernel_launch(void* const* d_in, const int* in_sizes, int n_in,
                              void* d_out, int out_size, void* d_ws, size_t ws_size,
                              hipStream_t stream) {
  const float* x  = (const float*)d_in[0];
  const float* wg = (const float*)d_in[1];
  const float* W1 = (const float*)d_in[2];
  const float* b1 = (const float*)d_in[3];
  const float* W2 = (const float*)d_in[4];
  const float* b2 = (const float*)d_in[5];
  float* out = (float*)d_out;

  char* ws = (char*)d_ws;
  int*   counts     = (int*)(ws + 0);       // [8]
  int*   cnt_off    = counts;               // [16]: counts then offsets
  int*   offsets    = (int*)(ws + 32);      // [8]
  int*   cursor     = (int*)(ws + 64);      // [8]
  float* importance = (float*)(ws + 96);    // [8]
  float* gates   = (float*)(ws + 256);            // 4096*2 f32
  int*   tidx    = (int*)(ws + 256 + 32768);
  int*   pos     = (int*)(ws + 256 + 65536);
  int*   row_ids = (int*)(ws + 256 + 98304);
  const size_t base = 262144;
  bf16* x_bf = (bf16*)(ws + base);                        //  6,291,456 B
  bf16* W1t  = (bf16*)(ws + base + 6291456);              // 25,165,824 B
  bf16* W2t  = (bf16*)(ws + base + 31457280);             // 25,165,824 B
  bf16* h_bf = (bf16*)(ws + base + 56623104);             // 33,554,432 B
  bf16* z_bf = (bf16*)(ws + base);                        // aliases x_bf/W1t (dead by GEMM2)

  hipMemsetAsync(ws, 0, 256, stream);  // counts / offsets / cursor / importance

  cvt_x_kernel<<<dim3(3072), 256, 0, stream>>>(x, x_bf);
  transpose_cvt<<<dim3(D_H / 64,  D_IN / 64, E_EXP), 256, 0, stream>>>(W1, W1t, D_IN, D_H);
  transpose_cvt<<<dim3(D_OUT / 64, D_H / 64, E_EXP), 256, 0, stream>>>(W2, W2t, D_H, D_OUT);
  gate_kernel<<<dim3(1024), 256, 0, stream>>>(x, wg, gates, tidx, counts, importance);
  finalize_gate<<<dim3(1), 64, 0, stream>>>(counts, offsets, importance,
                                            out + (size_t)B_TOK * D_OUT);
  assign_kernel<<<dim3(16), 256, 0, stream>>>(tidx, offsets, cursor, row_ids, pos);
  gemm_mlp<D_IN, 128, true,  true ><<<dim3(D_H / 128,  64, E_EXP), 256, 0, stream>>>(
      x_bf, W1t, b1, h_bf, row_ids, cnt_off, D_H);
  gemm_mlp<D_H,  64,  false, false><<<dim3(D_OUT / 128, 128, E_EXP), 256, 0, stream>>>(
      h_bf, W2t, b2, z_bf, row_ids, cnt_off, D_OUT);
  combine_kernel<<<dim3(1024), 256, 0, stream>>>(z_bf, gates, pos, out);
}

// Round 2
// 194.752 us; speedup vs baseline: 1.7473x; 1.7473x over previous
//
#include <hip/hip_runtime.h>
#include <hip/hip_bf16.h>
#include <math.h>

typedef __hip_bfloat16 bf16;
typedef short v8s __attribute__((ext_vector_type(8)));
typedef float v4f __attribute__((ext_vector_type(4)));

#define B_TOK 4096
#define E_EXP 8
#define D_IN  768
#define D_H   2048
#define D_OUT 768

// ---------------------------------------------------------------- helpers
__device__ __forceinline__ void gl_lds16(const bf16* g, bf16* l) {
  __builtin_amdgcn_global_load_lds(
      (const __attribute__((address_space(1))) unsigned int*)g,
      (__attribute__((address_space(3))) unsigned int*)l, 16, 0, 0);
}

// ---------------------------------------------- fused x->bf16 + gating (no atomics)
// 1 wave per token. Writes xb (bf16 row), gates[2t], tidx[2t].
__global__ void gate_cvt_kernel(const float* __restrict__ x, const float* __restrict__ wg,
                                bf16* __restrict__ xb,
                                float* __restrict__ gates, int* __restrict__ tidx) {
  int gt = blockIdx.x * 256 + threadIdx.x;
  int tok = gt >> 6, l = gt & 63;
  const float* xr = x + (size_t)tok * D_IN;
  bf16* xbr = xb + (size_t)tok * D_IN;
  float acc[8] = {0.f,0.f,0.f,0.f,0.f,0.f,0.f,0.f};
  #pragma unroll
  for (int i = 0; i < 3; ++i) {
    int k0 = i * 256 + l * 4;
    float4 v = *(const float4*)(xr + k0);
    union { bf16 h[4]; uint2 u; } pk;
    pk.h[0] = __float2bfloat16(v.x); pk.h[1] = __float2bfloat16(v.y);
    pk.h[2] = __float2bfloat16(v.z); pk.h[3] = __float2bfloat16(v.w);
    *(uint2*)(xbr + k0) = pk.u;
    float xv[4] = {v.x, v.y, v.z, v.w};
    #pragma unroll
    for (int j = 0; j < 4; ++j) {
      const float* wr = wg + (size_t)(k0 + j) * 8;
      float4 w0 = *(const float4*)wr;
      float4 w1 = *(const float4*)(wr + 4);
      acc[0] += xv[j] * w0.x; acc[1] += xv[j] * w0.y;
      acc[2] += xv[j] * w0.z; acc[3] += xv[j] * w0.w;
      acc[4] += xv[j] * w1.x; acc[5] += xv[j] * w1.y;
      acc[6] += xv[j] * w1.z; acc[7] += xv[j] * w1.w;
    }
  }
  #pragma unroll
  for (int d = 1; d < 64; d <<= 1)
    #pragma unroll
    for (int e = 0; e < 8; ++e) acc[e] += __shfl_xor(acc[e], d);
  if (l == 0) {
    int i1 = 0; float v1 = acc[0];
    #pragma unroll
    for (int e = 1; e < 8; ++e) if (acc[e] > v1) { v1 = acc[e]; i1 = e; }
    int i2 = -1; float v2 = -1e30f;
    #pragma unroll
    for (int e = 0; e < 8; ++e) if (e != i1 && acc[e] > v2) { v2 = acc[e]; i2 = e; }
    float ex = __expf(v2 - v1);                 // <= 1
    float g1 = 1.f / (1.f + ex), g2 = ex / (1.f + ex);
    gates[2 * tok] = g1; gates[2 * tok + 1] = g2;
    tidx[2 * tok] = i1;  tidx[2 * tok + 1] = i2;
  }
}

// ---------------------------------------------- single-block: histogram + scan +
// deterministic slot assignment + counts/offsets + aux loss.  256 threads.
__global__ void finalize_kernel(const int* __restrict__ tidx, const float* __restrict__ gates,
                                int* __restrict__ cnt_off, int* __restrict__ row_ids,
                                int* __restrict__ pos, float* __restrict__ loss_out) {
  __shared__ int   hcnt[256][9];
  __shared__ float himp[256][9];
  __shared__ int   tot[8], off[8];
  __shared__ float itot[8];
  int t = threadIdx.x;
  #pragma unroll
  for (int e = 0; e < 8; ++e) { hcnt[t][e] = 0; himp[t][e] = 0.f; }
  __syncthreads();
  // local histogram: 32 entries per thread, in order
  for (int i = 0; i < 32; ++i) {
    int idx = t * 32 + i;
    int e = tidx[idx];
    hcnt[t][e] += 1;
    himp[t][e] += gates[idx];
  }
  __syncthreads();
  // per-expert exclusive scan across threads (8 scanner threads)
  if (t < 8) {
    int run = 0; float s = 0.f;
    for (int j = 0; j < 256; ++j) {
      int c = hcnt[j][t];
      hcnt[j][t] = run;
      run += c;
      s += himp[j][t];
    }
    tot[t] = run; itot[t] = s;
  }
  __syncthreads();
  if (t == 0) {
    int o = 0;
    float mi = 0.f, ml = 0.f;
    for (int e = 0; e < 8; ++e) {
      off[e] = o; o += tot[e];
      cnt_off[e] = tot[e]; cnt_off[8 + e] = off[e];
      mi += itot[e]; ml += (float)tot[e];
    }
    mi *= 0.125f; ml *= 0.125f;
    float vi = 0.f, vl = 0.f;
    for (int e = 0; e < 8; ++e) {
      float d = itot[e] - mi;        vi += d * d;
      float d2 = (float)tot[e] - ml; vl += d2 * d2;
    }
    vi /= 7.f; vl /= 7.f;
    *loss_out = 0.01f * (vi / (mi * mi + 1e-10f) + vl / (ml * ml + 1e-10f));
  }
  __syncthreads();
  // deterministic assignment, ordered by entry index
  for (int i = 0; i < 32; ++i) {
    int idx = t * 32 + i;
    int e = tidx[idx];
    int slot = off[e] + hcnt[t][e];
    hcnt[t][e] += 1;
    row_ids[slot] = idx >> 1;     // token id
    pos[idx] = slot;
  }
}

// ---------------------------------------------- W [E][K][N] f32 -> Wt [E][N][K] bf16
__global__ void transpose_cvt(const float* __restrict__ W, bf16* __restrict__ Wt,
                              int K, int N) {
  __shared__ bf16 tile[64][72];          // row stride 144 B (16B-aligned)
  int e = blockIdx.z;
  int k0 = blockIdx.y * 64, n0 = blockIdx.x * 64;
  const float* Wp = W + (size_t)e * K * N;
  bf16* Wtp = Wt + (size_t)e * N * K;
  int t = threadIdx.x;
  int cr = t >> 4;            // k-row 0..15
  int cc = (t & 15) * 4;      // n col
  #pragma unroll
  for (int p = 0; p < 4; ++p) {
    int kr = cr + p * 16;
    float4 v = *(const float4*)(Wp + (size_t)(k0 + kr) * N + n0 + cc);
    tile[cc + 0][kr] = __float2bfloat16(v.x);
    tile[cc + 1][kr] = __float2bfloat16(v.y);
    tile[cc + 2][kr] = __float2bfloat16(v.z);
    tile[cc + 3][kr] = __float2bfloat16(v.w);
  }
  __syncthreads();
  #pragma unroll
  for (int p = 0; p < 2; ++p) {
    int o = p * 256 + t;       // 0..511
    int n = o >> 3, k8 = (o & 7) * 8;
    v8s val = *(const v8s*)&tile[n][k8];
    *(v8s*)(Wtp + (size_t)(n0 + n) * K + k0 + k8) = val;
  }
}

// ---------------------------------------------------------------- grouped GEMM
// C[r][n] = act(sum_k A[r][k] * Wt[e][n][k] + bias[e][n]) -> bf16 Out[r][n]
// m97 structure: 2-barrier K-loop, global_load_lds width 16, XOR-(row&7) chunk swizzle.
template<int KDIM, int BM, bool GATHER, bool GELU>
__global__ __launch_bounds__(256)
void gemm_mlp(const bf16* __restrict__ Ab, const bf16* __restrict__ Wt,
              const float* __restrict__ bias, bf16* __restrict__ Outb,
              const int* __restrict__ row_ids, const int* __restrict__ cnt_off,
              const int N) {
  constexpr int BK = 64;
  constexpr int BN = 128;
  constexpr int ITA = BM / 32;   // global_load_lds per wave for A
  constexpr int FM  = BM / 32;   // 16-row frags per wave in M
  __shared__ __align__(16) bf16 lsA[BM * BK];
  __shared__ __align__(16) bf16 lsB[BN * BK];
  const int e = blockIdx.z;
  const int cnt = cnt_off[e];
  const int rowb = blockIdx.y;
  if (rowb * BM >= cnt) return;
  const int off = cnt_off[8 + e];
  const int colb = blockIdx.x;
  const int t = (int)threadIdx.x, w = t >> 6, l = t & 63;
  const int cs = (l & 7) ^ (l >> 3);         // pre-swizzled source chunk col
  const bf16* gA[ITA];
  const bf16* gB[4];
  #pragma unroll
  for (int it = 0; it < ITA; ++it) {
    int rt = (it * 4 + w) * 8 + (l >> 3);    // tile row; rt&7 == l>>3
    int r = rowb * BM + rt;
    int rc = r < cnt ? r : cnt - 1;
    long arow = GATHER ? (long)row_ids[off + rc] : (long)(off + rc);
    gA[it] = Ab + arow * (long)KDIM + cs * 8;
  }
  #pragma unroll
  for (int it = 0; it < 4; ++it) {
    int rt = (it * 4 + w) * 8 + (l >> 3);
    gB[it] = Wt + ((size_t)e * N + (size_t)colb * BN + rt) * KDIM + cs * 8;
  }
  v4f acc[FM][4] = {};
  const int wm = w >> 1, wn = w & 1;
  for (int ks = 0; ks < KDIM / BK; ++ks) {
    const int k0 = ks * BK;
    #pragma unroll
    for (int it = 0; it < ITA; ++it) gl_lds16(gA[it] + k0, lsA + (it * 4 + w) * 512);
    #pragma unroll
    for (int it = 0; it < 4; ++it)   gl_lds16(gB[it] + k0, lsB + (it * 4 + w) * 512);
    __syncthreads();   // compiler drains vmcnt before barrier
    #pragma unroll
    for (int kk = 0; kk < 2; ++kk) {
      v8s af[FM], bfr[4];
      #pragma unroll
      for (int fm = 0; fm < FM; ++fm) {
        int row = wm * (BM / 2) + fm * 16 + (l & 15);
        int cg = kk * 4 + (l >> 4);
        af[fm] = *(const v8s*)(lsA + row * BK + ((cg ^ (row & 7)) << 3));
      }
      #pragma unroll
      for (int fn = 0; fn < 4; ++fn) {
        int row = wn * 64 + fn * 16 + (l & 15);
        int cg = kk * 4 + (l >> 4);
        bfr[fn] = *(const v8s*)(lsB + row * BK + ((cg ^ (row & 7)) << 3));
      }
      #pragma unroll
      for (int fm = 0; fm < FM; ++fm)
        #pragma unroll
        for (int fn = 0; fn < 4; ++fn)
          acc[fm][fn] = __builtin_amdgcn_mfma_f32_16x16x32_bf16(af[fm], bfr[fn], acc[fm][fn], 0, 0, 0);
    }
    __syncthreads();
  }
  // epilogue: bias (+gelu) -> bf16
  const float* bp = bias + (size_t)e * N + (size_t)colb * BN;
  #pragma unroll
  for (int fm = 0; fm < FM; ++fm) {
    int lr0 = wm * (BM / 2) + fm * 16 + (l >> 4) * 4;
    #pragma unroll
    for (int fn = 0; fn < 4; ++fn) {
      int lcol = wn * 64 + fn * 16 + (l & 15);
      float bv = bp[lcol];
      #pragma unroll
      for (int q = 0; q < 4; ++q) {
        int lr = lr0 + q;
        int r = rowb * BM + lr;
        if (r < cnt) {
          float v = acc[fm][fn][q] + bv;
          if (GELU) {
            float u = 0.7978845608028654f * (v + 0.044715f * v * v * v);
            float th = 1.f - 2.f / (__expf(2.f * u) + 1.f);   // tanh(u)
            v = 0.5f * v * (1.f + th);
          }
          Outb[(size_t)(off + r) * N + (size_t)colb * BN + lcol] = __float2bfloat16(v);
        }
      }
    }
  }
}

// ---------------------------------------------------------------- combine
__global__ void combine_kernel(const bf16* __restrict__ z, const float* __restrict__ gates,
                               const int* __restrict__ pos, float* __restrict__ y) {
  int gt = blockIdx.x * 256 + threadIdx.x;
  int tok = gt >> 6, l = gt & 63;
  if (tok >= B_TOK) return;
  const bf16* z1 = z + (size_t)pos[2 * tok] * D_OUT;
  const bf16* z2 = z + (size_t)pos[2 * tok + 1] * D_OUT;
  float g1 = gates[2 * tok], g2 = gates[2 * tok + 1];
  float a[12], b[12];
  float m1 = -1e30f, m2 = -1e30f;
  #pragma unroll
  for (int i = 0; i < 12; ++i) {
    a[i] = __bfloat162float(z1[l + 64 * i]);
    b[i] = __bfloat162float(z2[l + 64 * i]);
    m1 = fmaxf(m1, a[i]); m2 = fmaxf(m2, b[i]);
  }
  #pragma unroll
  for (int d = 1; d < 64; d <<= 1) {
    m1 = fmaxf(m1, __shfl_xor(m1, d));
    m2 = fmaxf(m2, __shfl_xor(m2, d));
  }
  float s1 = 0.f, s2 = 0.f;
  #pragma unroll
  for (int i = 0; i < 12; ++i) { s1 += __expf(a[i] - m1); s2 += __expf(b[i] - m2); }
  #pragma unroll
  for (int d = 1; d < 64; d <<= 1) { s1 += __shfl_xor(s1, d); s2 += __shfl_xor(s2, d); }
  float c1 = g1 / s1, c2 = g2 / s2;
  #pragma unroll
  for (int i = 0; i < 12; ++i) {
    float cmb = c1 * __expf(a[i] - m1) + c2 * __expf(b[i] - m2);
    y[(size_t)tok * D_OUT + l + 64 * i] = logf(cmb == 0.f ? 2.2204460492503131e-16f : cmb);
  }
}

// ---------------------------------------------------------------- launch
extern "C" void kernel_launch(void* const* d_in, const int* in_sizes, int n_in,
                              void* d_out, int out_size, void* d_ws, size_t ws_size,
                              hipStream_t stream) {
  const float* x  = (const float*)d_in[0];
  const float* wg = (const float*)d_in[1];
  const float* W1 = (const float*)d_in[2];
  const float* b1 = (const float*)d_in[3];
  const float* W2 = (const float*)d_in[4];
  const float* b2 = (const float*)d_in[5];
  float* out = (float*)d_out;

  char* ws = (char*)d_ws;
  int*   cnt_off = (int*)(ws + 0);                // [16]: counts then offsets
  float* gates   = (float*)(ws + 256);            // 4096*2 f32
  int*   tidx    = (int*)(ws + 256 + 32768);
  int*   pos     = (int*)(ws + 256 + 65536);
  int*   row_ids = (int*)(ws + 256 + 98304);
  const size_t base = 262144;
  bf16* x_bf = (bf16*)(ws + base);                        //  6,291,456 B
  bf16* W1t  = (bf16*)(ws + base + 6291456);              // 25,165,824 B
  bf16* W2t  = (bf16*)(ws + base + 31457280);             // 25,165,824 B
  bf16* h_bf = (bf16*)(ws + base + 56623104);             // 33,554,432 B
  bf16* z_bf = (bf16*)(ws + base);                        // aliases x_bf/W1t (dead by GEMM2)

  transpose_cvt<<<dim3(D_H / 64,  D_IN / 64, E_EXP), 256, 0, stream>>>(W1, W1t, D_IN, D_H);
  transpose_cvt<<<dim3(D_OUT / 64, D_H / 64, E_EXP), 256, 0, stream>>>(W2, W2t, D_H, D_OUT);
  gate_cvt_kernel<<<dim3(1024), 256, 0, stream>>>(x, wg, x_bf, gates, tidx);
  finalize_kernel<<<dim3(1), 256, 0, stream>>>(tidx, gates, cnt_off, row_ids, pos,
                                               out + (size_t)B_TOK * D_OUT);
  gemm_mlp<D_IN, 128, true,  true ><<<dim3(D_H / 128,  64, E_EXP), 256, 0, stream>>>(
      x_bf, W1t, b1, h_bf, row_ids, cnt_off, D_H);
  gemm_mlp<D_H,  64,  false, false><<<dim3(D_OUT / 128, 128, E_EXP), 256, 0, stream>>>(
      h_bf, W2t, b2, z_bf, row_ids, cnt_off, D_OUT);
  combine_kernel<<<dim3(1024), 256, 0, stream>>>(z_bf, gates, pos, out);
}

// Round 3
// 181.046 us; speedup vs baseline: 1.8796x; 1.0757x over previous
//
#include <hip/hip_runtime.h>
#include <hip/hip_bf16.h>
#include <math.h>

typedef __hip_bfloat16 bf16;
typedef short v8s __attribute__((ext_vector_type(8)));
typedef float v4f __attribute__((ext_vector_type(4)));

#define B_TOK 4096
#define E_EXP 8
#define D_IN  768
#define D_H   2048
#define D_OUT 768
#define MAXT  72      // max M-tiles of 128 over all experts (64 + 7 rounding, padded)

// ---------------------------------------------------------------- helpers
__device__ __forceinline__ void gl_lds16(const bf16* g, bf16* l) {
  __builtin_amdgcn_global_load_lds(
      (const __attribute__((address_space(1))) unsigned int*)g,
      (__attribute__((address_space(3))) unsigned int*)l, 16, 0, 0);
}

// ---------------------------------------------- fused x->bf16 + gating (no atomics)
__global__ void gate_cvt_kernel(const float* __restrict__ x, const float* __restrict__ wg,
                                bf16* __restrict__ xb,
                                float* __restrict__ gates, int* __restrict__ tidx) {
  int gt = blockIdx.x * 256 + threadIdx.x;
  int tok = gt >> 6, l = gt & 63;
  const float* xr = x + (size_t)tok * D_IN;
  bf16* xbr = xb + (size_t)tok * D_IN;
  float acc[8] = {0.f,0.f,0.f,0.f,0.f,0.f,0.f,0.f};
  #pragma unroll
  for (int i = 0; i < 3; ++i) {
    int k0 = i * 256 + l * 4;
    float4 v = *(const float4*)(xr + k0);
    union { bf16 h[4]; uint2 u; } pk;
    pk.h[0] = __float2bfloat16(v.x); pk.h[1] = __float2bfloat16(v.y);
    pk.h[2] = __float2bfloat16(v.z); pk.h[3] = __float2bfloat16(v.w);
    *(uint2*)(xbr + k0) = pk.u;
    float xv[4] = {v.x, v.y, v.z, v.w};
    #pragma unroll
    for (int j = 0; j < 4; ++j) {
      const float* wr = wg + (size_t)(k0 + j) * 8;
      float4 w0 = *(const float4*)wr;
      float4 w1 = *(const float4*)(wr + 4);
      acc[0] += xv[j] * w0.x; acc[1] += xv[j] * w0.y;
      acc[2] += xv[j] * w0.z; acc[3] += xv[j] * w0.w;
      acc[4] += xv[j] * w1.x; acc[5] += xv[j] * w1.y;
      acc[6] += xv[j] * w1.z; acc[7] += xv[j] * w1.w;
    }
  }
  #pragma unroll
  for (int d = 1; d < 64; d <<= 1)
    #pragma unroll
    for (int e = 0; e < 8; ++e) acc[e] += __shfl_xor(acc[e], d);
  if (l == 0) {
    int i1 = 0; float v1 = acc[0];
    #pragma unroll
    for (int e = 1; e < 8; ++e) if (acc[e] > v1) { v1 = acc[e]; i1 = e; }
    int i2 = -1; float v2 = -1e30f;
    #pragma unroll
    for (int e = 0; e < 8; ++e) if (e != i1 && acc[e] > v2) { v2 = acc[e]; i2 = e; }
    float ex = __expf(v2 - v1);
    float g1 = 1.f / (1.f + ex), g2 = ex / (1.f + ex);
    gates[2 * tok] = g1; gates[2 * tok + 1] = g2;
    tidx[2 * tok] = i1;  tidx[2 * tok + 1] = i2;
  }
}

// ---------------------------------------------- single-block: histogram + scan +
// slot assignment + counts/offsets + tile map + aux loss.  256 threads.
__global__ void finalize_kernel(const int* __restrict__ tidx, const float* __restrict__ gates,
                                int* __restrict__ cnt_off, int* __restrict__ row_ids,
                                int* __restrict__ pos, int* __restrict__ tmap,
                                float* __restrict__ loss_out) {
  __shared__ int   hcnt[256][9];
  __shared__ float himp[256][9];
  __shared__ int   tot[8], off[8];
  __shared__ float itot[8];
  int t = threadIdx.x;
  #pragma unroll
  for (int e = 0; e < 8; ++e) { hcnt[t][e] = 0; himp[t][e] = 0.f; }
  __syncthreads();
  for (int i = 0; i < 32; ++i) {
    int idx = t * 32 + i;
    int e = tidx[idx];
    hcnt[t][e] += 1;
    himp[t][e] += gates[idx];
  }
  __syncthreads();
  if (t < 8) {
    int run = 0; float s = 0.f;
    for (int j = 0; j < 256; ++j) {
      int c = hcnt[j][t];
      hcnt[j][t] = run;
      run += c;
      s += himp[j][t];
    }
    tot[t] = run; itot[t] = s;
  }
  __syncthreads();
  if (t == 0) {
    int o = 0;
    float mi = 0.f, ml = 0.f;
    for (int e = 0; e < 8; ++e) {
      off[e] = o; o += tot[e];
      cnt_off[e] = tot[e]; cnt_off[8 + e] = off[e];
      mi += itot[e]; ml += (float)tot[e];
    }
    mi *= 0.125f; ml *= 0.125f;
    float vi = 0.f, vl = 0.f;
    for (int e = 0; e < 8; ++e) {
      float d = itot[e] - mi;        vi += d * d;
      float d2 = (float)tot[e] - ml; vl += d2 * d2;
    }
    vi /= 7.f; vl /= 7.f;
    *loss_out = 0.01f * (vi / (mi * mi + 1e-10f) + vl / (ml * ml + 1e-10f));
    // compact tile map: tmap[i] = expert, tmap[MAXT+i] = row-block within expert
    int nt = 0;
    for (int e = 0; e < 8; ++e)
      for (int tt = 0; tt < (tot[e] + 127) >> 7; ++tt) {
        tmap[nt] = e; tmap[MAXT + nt] = tt; ++nt;
      }
    for (; nt < MAXT; ++nt) tmap[nt] = -1;
  }
  __syncthreads();
  for (int i = 0; i < 32; ++i) {
    int idx = t * 32 + i;
    int e = tidx[idx];
    int slot = off[e] + hcnt[t][e];
    hcnt[t][e] += 1;
    row_ids[slot] = idx >> 1;
    pos[idx] = slot;
  }
}

// ---------------------------------------------- W [E][K][N] f32 -> Wt [E][N][K] bf16
__global__ void transpose_cvt(const float* __restrict__ W, bf16* __restrict__ Wt,
                              int K, int N) {
  __shared__ bf16 tile[64][72];
  int e = blockIdx.z;
  int k0 = blockIdx.y * 64, n0 = blockIdx.x * 64;
  const float* Wp = W + (size_t)e * K * N;
  bf16* Wtp = Wt + (size_t)e * N * K;
  int t = threadIdx.x;
  int cr = t >> 4;
  int cc = (t & 15) * 4;
  #pragma unroll
  for (int p = 0; p < 4; ++p) {
    int kr = cr + p * 16;
    float4 v = *(const float4*)(Wp + (size_t)(k0 + kr) * N + n0 + cc);
    tile[cc + 0][kr] = __float2bfloat16(v.x);
    tile[cc + 1][kr] = __float2bfloat16(v.y);
    tile[cc + 2][kr] = __float2bfloat16(v.z);
    tile[cc + 3][kr] = __float2bfloat16(v.w);
  }
  __syncthreads();
  #pragma unroll
  for (int p = 0; p < 2; ++p) {
    int o = p * 256 + t;
    int n = o >> 3, k8 = (o & 7) * 8;
    v8s val = *(const v8s*)&tile[n][k8];
    *(v8s*)(Wtp + (size_t)(n0 + n) * K + k0 + k8) = val;
  }
}

// ---------------------------------------------------------------- grouped GEMM
// Double-buffered min-2-phase K-loop (T3-minimum): prefetch next K-tile into the
// other LDS buffer BEFORE computing current; one barrier per K-step.
template<int KDIM, bool GATHER, bool GELU>
__global__ __launch_bounds__(256)
void gemm_mlp(const bf16* __restrict__ Ab, const bf16* __restrict__ Wt,
              const float* __restrict__ bias, bf16* __restrict__ Outb,
              const int* __restrict__ row_ids, const int* __restrict__ cnt_off,
              const int* __restrict__ tmap, const int N) {
  constexpr int BK = 64, BM = 128, BN = 128;
  constexpr int NK = KDIM / BK;
  static_assert(NK % 2 == 0, "NK even");
  __shared__ __align__(16) bf16 lsA0[BM * BK], lsB0[BN * BK];
  __shared__ __align__(16) bf16 lsA1[BM * BK], lsB1[BN * BK];
  const int ti = blockIdx.y;
  const int e = tmap[ti];
  if (e < 0) return;
  const int rowb = tmap[MAXT + ti];
  const int cnt = cnt_off[e];
  const int off = cnt_off[8 + e];
  const int colb = blockIdx.x;
  const int t = (int)threadIdx.x, w = t >> 6, l = t & 63;
  const int cs = (l & 7) ^ (l >> 3);         // pre-swizzled source chunk col
  const bf16* gA[4];
  const bf16* gB[4];
  #pragma unroll
  for (int it = 0; it < 4; ++it) {
    int rt = (it * 4 + w) * 8 + (l >> 3);
    int r = rowb * BM + rt;
    int rc = r < cnt ? r : cnt - 1;
    long arow = GATHER ? (long)row_ids[off + rc] : (long)(off + rc);
    gA[it] = Ab + arow * (long)KDIM + cs * 8;
  }
  #pragma unroll
  for (int it = 0; it < 4; ++it) {
    int rt = (it * 4 + w) * 8 + (l >> 3);
    gB[it] = Wt + ((size_t)e * N + (size_t)colb * BN + rt) * KDIM + cs * 8;
  }
  v4f acc[4][4] = {};
  const int wm = w >> 1, wn = w & 1;

#define STAGE(lA, lB, k0) do {                                             \
    _Pragma("unroll")                                                      \
    for (int it = 0; it < 4; ++it) gl_lds16(gA[it] + (k0), (lA) + (it * 4 + w) * 512); \
    _Pragma("unroll")                                                      \
    for (int it = 0; it < 4; ++it) gl_lds16(gB[it] + (k0), (lB) + (it * 4 + w) * 512); \
  } while (0)

#define COMPUTE(lA, lB) do {                                               \
    _Pragma("unroll")                                                      \
    for (int kk = 0; kk < 2; ++kk) {                                       \
      v8s af[4], bfr[4];                                                   \
      _Pragma("unroll")                                                    \
      for (int fm = 0; fm < 4; ++fm) {                                     \
        int row = wm * 64 + fm * 16 + (l & 15);                            \
        int cg = kk * 4 + (l >> 4);                                        \
        af[fm] = *(const v8s*)((lA) + row * BK + ((cg ^ (row & 7)) << 3)); \
      }                                                                    \
      _Pragma("unroll")                                                    \
      for (int fn = 0; fn < 4; ++fn) {                                     \
        int row = wn * 64 + fn * 16 + (l & 15);                            \
        int cg = kk * 4 + (l >> 4);                                        \
        bfr[fn] = *(const v8s*)((lB) + row * BK + ((cg ^ (row & 7)) << 3));\
      }                                                                    \
      _Pragma("unroll")                                                    \
      for (int fm = 0; fm < 4; ++fm)                                       \
        _Pragma("unroll")                                                  \
        for (int fn = 0; fn < 4; ++fn)                                     \
          acc[fm][fn] = __builtin_amdgcn_mfma_f32_16x16x32_bf16(af[fm], bfr[fn], acc[fm][fn], 0, 0, 0); \
    }                                                                      \
  } while (0)

  STAGE(lsA0, lsB0, 0);
  __syncthreads();
  #pragma unroll 1
  for (int ks = 0; ks < NK; ks += 2) {
    if (ks + 1 < NK) STAGE(lsA1, lsB1, (ks + 1) * BK);
    COMPUTE(lsA0, lsB0);
    __syncthreads();                       // drains vmcnt: buf1 ready, buf0 free
    if (ks + 2 < NK) STAGE(lsA0, lsB0, (ks + 2) * BK);
    COMPUTE(lsA1, lsB1);
    __syncthreads();
  }
#undef STAGE
#undef COMPUTE

  // epilogue: bias (+gelu) -> bf16
  const float* bp = bias + (size_t)e * N + (size_t)colb * BN;
  #pragma unroll
  for (int fm = 0; fm < 4; ++fm) {
    int lr0 = wm * 64 + fm * 16 + (l >> 4) * 4;
    #pragma unroll
    for (int fn = 0; fn < 4; ++fn) {
      int lcol = wn * 64 + fn * 16 + (l & 15);
      float bv = bp[lcol];
      #pragma unroll
      for (int q = 0; q < 4; ++q) {
        int lr = lr0 + q;
        int r = rowb * BM + lr;
        if (r < cnt) {
          float v = acc[fm][fn][q] + bv;
          if (GELU) {
            float u = 0.7978845608028654f * (v + 0.044715f * v * v * v);
            float th = 1.f - 2.f / (__expf(2.f * u) + 1.f);   // tanh(u)
            v = 0.5f * v * (1.f + th);
          }
          Outb[(size_t)(off + r) * N + (size_t)colb * BN + lcol] = __float2bfloat16(v);
        }
      }
    }
  }
}

// ---------------------------------------------------------------- combine
__global__ void combine_kernel(const bf16* __restrict__ z, const float* __restrict__ gates,
                               const int* __restrict__ pos, float* __restrict__ y) {
  int gt = blockIdx.x * 256 + threadIdx.x;
  int tok = gt >> 6, l = gt & 63;
  if (tok >= B_TOK) return;
  const bf16* z1 = z + (size_t)pos[2 * tok] * D_OUT;
  const bf16* z2 = z + (size_t)pos[2 * tok + 1] * D_OUT;
  float g1 = gates[2 * tok], g2 = gates[2 * tok + 1];
  float a[12], b[12];
  float m1 = -1e30f, m2 = -1e30f;
  #pragma unroll
  for (int i = 0; i < 12; ++i) {
    a[i] = __bfloat162float(z1[l + 64 * i]);
    b[i] = __bfloat162float(z2[l + 64 * i]);
    m1 = fmaxf(m1, a[i]); m2 = fmaxf(m2, b[i]);
  }
  #pragma unroll
  for (int d = 1; d < 64; d <<= 1) {
    m1 = fmaxf(m1, __shfl_xor(m1, d));
    m2 = fmaxf(m2, __shfl_xor(m2, d));
  }
  float s1 = 0.f, s2 = 0.f;
  #pragma unroll
  for (int i = 0; i < 12; ++i) { s1 += __expf(a[i] - m1); s2 += __expf(b[i] - m2); }
  #pragma unroll
  for (int d = 1; d < 64; d <<= 1) { s1 += __shfl_xor(s1, d); s2 += __shfl_xor(s2, d); }
  float c1 = g1 / s1, c2 = g2 / s2;
  #pragma unroll
  for (int i = 0; i < 12; ++i) {
    float cmb = c1 * __expf(a[i] - m1) + c2 * __expf(b[i] - m2);
    y[(size_t)tok * D_OUT + l + 64 * i] = logf(cmb == 0.f ? 2.2204460492503131e-16f : cmb);
  }
}

// ---------------------------------------------------------------- launch
extern "C" void kernel_launch(void* const* d_in, const int* in_sizes, int n_in,
                              void* d_out, int out_size, void* d_ws, size_t ws_size,
                              hipStream_t stream) {
  const float* x  = (const float*)d_in[0];
  const float* wg = (const float*)d_in[1];
  const float* W1 = (const float*)d_in[2];
  const float* b1 = (const float*)d_in[3];
  const float* W2 = (const float*)d_in[4];
  const float* b2 = (const float*)d_in[5];
  float* out = (float*)d_out;

  char* ws = (char*)d_ws;
  int*   cnt_off = (int*)(ws + 0);                // [16]: counts then offsets
  float* gates   = (float*)(ws + 256);            // 4096*2 f32
  int*   tidx    = (int*)(ws + 256 + 32768);
  int*   pos     = (int*)(ws + 256 + 65536);
  int*   row_ids = (int*)(ws + 256 + 98304);
  int*   tmap    = (int*)(ws + 256 + 131072);     // [2*MAXT]
  const size_t base = 262144;
  bf16* x_bf = (bf16*)(ws + base);                        //  6,291,456 B
  bf16* W1t  = (bf16*)(ws + base + 6291456);              // 25,165,824 B
  bf16* W2t  = (bf16*)(ws + base + 31457280);             // 25,165,824 B
  bf16* h_bf = (bf16*)(ws + base + 56623104);             // 33,554,432 B
  bf16* z_bf = (bf16*)(ws + base);                        // aliases x_bf/W1t (dead by GEMM2)

  transpose_cvt<<<dim3(D_H / 64,  D_IN / 64, E_EXP), 256, 0, stream>>>(W1, W1t, D_IN, D_H);
  transpose_cvt<<<dim3(D_OUT / 64, D_H / 64, E_EXP), 256, 0, stream>>>(W2, W2t, D_H, D_OUT);
  gate_cvt_kernel<<<dim3(1024), 256, 0, stream>>>(x, wg, x_bf, gates, tidx);
  finalize_kernel<<<dim3(1), 256, 0, stream>>>(tidx, gates, cnt_off, row_ids, pos, tmap,
                                               out + (size_t)B_TOK * D_OUT);
  gemm_mlp<D_IN, true,  true ><<<dim3(D_H / 128,  MAXT), 256, 0, stream>>>(
      x_bf, W1t, b1, h_bf, row_ids, cnt_off, tmap, D_H);
  gemm_mlp<D_H,  false, false><<<dim3(D_OUT / 128, MAXT), 256, 0, stream>>>(
      h_bf, W2t, b2, z_bf, row_ids, cnt_off, tmap, D_OUT);
  combine_kernel<<<dim3(1024), 256, 0, stream>>>(z_bf, gates, pos, out);
}

// Round 4
// 177.350 us; speedup vs baseline: 1.9188x; 1.0208x over previous
//
#include <hip/hip_runtime.h>
#include <hip/hip_bf16.h>
#include <math.h>

typedef __hip_bfloat16 bf16;
typedef short v8s __attribute__((ext_vector_type(8)));
typedef float v4f __attribute__((ext_vector_type(4)));

#define B_TOK 4096
#define E_EXP 8
#define D_IN  768
#define D_H   2048
#define D_OUT 768
#define MAXT  72      // max M-tiles of 128 over all experts (64 + 7 rounding, padded)

// ---------------------------------------------------------------- helpers
__device__ __forceinline__ void gl_lds16(const bf16* g, bf16* l) {
  __builtin_amdgcn_global_load_lds(
      (const __attribute__((address_space(1))) unsigned int*)g,
      (__attribute__((address_space(3))) unsigned int*)l, 16, 0, 0);
}

// ---------------------------------------------- fused x->bf16 + gating (no atomics)
__global__ void gate_cvt_kernel(const float* __restrict__ x, const float* __restrict__ wg,
                                bf16* __restrict__ xb,
                                float* __restrict__ gates, int* __restrict__ tidx) {
  int gt = blockIdx.x * 256 + threadIdx.x;
  int tok = gt >> 6, l = gt & 63;
  const float* xr = x + (size_t)tok * D_IN;
  bf16* xbr = xb + (size_t)tok * D_IN;
  float acc[8] = {0.f,0.f,0.f,0.f,0.f,0.f,0.f,0.f};
  #pragma unroll
  for (int i = 0; i < 3; ++i) {
    int k0 = i * 256 + l * 4;
    float4 v = *(const float4*)(xr + k0);
    union { bf16 h[4]; uint2 u; } pk;
    pk.h[0] = __float2bfloat16(v.x); pk.h[1] = __float2bfloat16(v.y);
    pk.h[2] = __float2bfloat16(v.z); pk.h[3] = __float2bfloat16(v.w);
    *(uint2*)(xbr + k0) = pk.u;
    float xv[4] = {v.x, v.y, v.z, v.w};
    #pragma unroll
    for (int j = 0; j < 4; ++j) {
      const float* wr = wg + (size_t)(k0 + j) * 8;
      float4 w0 = *(const float4*)wr;
      float4 w1 = *(const float4*)(wr + 4);
      acc[0] += xv[j] * w0.x; acc[1] += xv[j] * w0.y;
      acc[2] += xv[j] * w0.z; acc[3] += xv[j] * w0.w;
      acc[4] += xv[j] * w1.x; acc[5] += xv[j] * w1.y;
      acc[6] += xv[j] * w1.z; acc[7] += xv[j] * w1.w;
    }
  }
  #pragma unroll
  for (int d = 1; d < 64; d <<= 1)
    #pragma unroll
    for (int e = 0; e < 8; ++e) acc[e] += __shfl_xor(acc[e], d);
  if (l == 0) {
    int i1 = 0; float v1 = acc[0];
    #pragma unroll
    for (int e = 1; e < 8; ++e) if (acc[e] > v1) { v1 = acc[e]; i1 = e; }
    int i2 = -1; float v2 = -1e30f;
    #pragma unroll
    for (int e = 0; e < 8; ++e) if (e != i1 && acc[e] > v2) { v2 = acc[e]; i2 = e; }
    float ex = __expf(v2 - v1);
    float g1 = 1.f / (1.f + ex), g2 = ex / (1.f + ex);
    gates[2 * tok] = g1; gates[2 * tok + 1] = g2;
    tidx[2 * tok] = i1;  tidx[2 * tok + 1] = i2;
  }
}

// ---------------------------------------------- single-block: histogram + scan +
// slot assignment + counts/offsets + tile map + aux loss.  256 threads.
__global__ void finalize_kernel(const int* __restrict__ tidx, const float* __restrict__ gates,
                                int* __restrict__ cnt_off, int* __restrict__ row_ids,
                                int* __restrict__ pos, int* __restrict__ tmap,
                                float* __restrict__ loss_out) {
  __shared__ int   hcnt[256][9];
  __shared__ float himp[256][9];
  __shared__ int   tot[8], off[8];
  __shared__ float itot[8];
  int t = threadIdx.x;
  #pragma unroll
  for (int e = 0; e < 8; ++e) { hcnt[t][e] = 0; himp[t][e] = 0.f; }
  __syncthreads();
  for (int i = 0; i < 32; ++i) {
    int idx = t * 32 + i;
    int e = tidx[idx];
    hcnt[t][e] += 1;
    himp[t][e] += gates[idx];
  }
  __syncthreads();
  if (t < 8) {
    int run = 0; float s = 0.f;
    for (int j = 0; j < 256; ++j) {
      int c = hcnt[j][t];
      hcnt[j][t] = run;
      run += c;
      s += himp[j][t];
    }
    tot[t] = run; itot[t] = s;
  }
  __syncthreads();
  if (t == 0) {
    int o = 0;
    float mi = 0.f, ml = 0.f;
    for (int e = 0; e < 8; ++e) {
      off[e] = o; o += tot[e];
      cnt_off[e] = tot[e]; cnt_off[8 + e] = off[e];
      mi += itot[e]; ml += (float)tot[e];
    }
    mi *= 0.125f; ml *= 0.125f;
    float vi = 0.f, vl = 0.f;
    for (int e = 0; e < 8; ++e) {
      float d = itot[e] - mi;        vi += d * d;
      float d2 = (float)tot[e] - ml; vl += d2 * d2;
    }
    vi /= 7.f; vl /= 7.f;
    *loss_out = 0.01f * (vi / (mi * mi + 1e-10f) + vl / (ml * ml + 1e-10f));
    int nt = 0;
    for (int e = 0; e < 8; ++e)
      for (int tt = 0; tt < (tot[e] + 127) >> 7; ++tt) {
        tmap[nt] = e; tmap[MAXT + nt] = tt; ++nt;
      }
    for (; nt < MAXT; ++nt) tmap[nt] = -1;
  }
  __syncthreads();
  for (int i = 0; i < 32; ++i) {
    int idx = t * 32 + i;
    int e = tidx[idx];
    int slot = off[e] + hcnt[t][e];
    hcnt[t][e] += 1;
    row_ids[slot] = idx >> 1;
    pos[idx] = slot;
  }
}

// ---------------------------------------------- W [E][K][N] f32 -> Wt [E][N][K] bf16
__global__ void transpose_cvt(const float* __restrict__ W, bf16* __restrict__ Wt,
                              int K, int N) {
  __shared__ bf16 tile[64][72];
  int e = blockIdx.z;
  int k0 = blockIdx.y * 64, n0 = blockIdx.x * 64;
  const float* Wp = W + (size_t)e * K * N;
  bf16* Wtp = Wt + (size_t)e * N * K;
  int t = threadIdx.x;
  int cr = t >> 4;
  int cc = (t & 15) * 4;
  #pragma unroll
  for (int p = 0; p < 4; ++p) {
    int kr = cr + p * 16;
    float4 v = *(const float4*)(Wp + (size_t)(k0 + kr) * N + n0 + cc);
    tile[cc + 0][kr] = __float2bfloat16(v.x);
    tile[cc + 1][kr] = __float2bfloat16(v.y);
    tile[cc + 2][kr] = __float2bfloat16(v.z);
    tile[cc + 3][kr] = __float2bfloat16(v.w);
  }
  __syncthreads();
  #pragma unroll
  for (int p = 0; p < 2; ++p) {
    int o = p * 256 + t;
    int n = o >> 3, k8 = (o & 7) * 8;
    v8s val = *(const v8s*)&tile[n][k8];
    *(v8s*)(Wtp + (size_t)(n0 + n) * K + k0 + k8) = val;
  }
}

// ---------------------------------------------------------------- grouped GEMM
// T3+T4: 4-buffer depth-3 prefetch, counted vmcnt (24/16/8/0), raw s_barrier.
// Fragment/swizzle math identical to the verified R2/R3 kernel.
template<int KDIM, bool GATHER, bool GELU>
__global__ __launch_bounds__(256)
void gemm_mlp(const bf16* __restrict__ Ab, const bf16* __restrict__ Wt,
              const float* __restrict__ bias, bf16* __restrict__ Outb,
              const int* __restrict__ row_ids, const int* __restrict__ cnt_off,
              const int* __restrict__ tmap, const int N) {
  constexpr int BK = 64, BM = 128, BN = 128;
  constexpr int NK = KDIM / BK;
  static_assert(NK % 4 == 0, "NK multiple of 4");
  __shared__ __align__(16) bf16 lds[4][2][BM * BK];   // [buf][A=0/B=1][8192] = 128 KiB
  const int ti = blockIdx.y;
  const int e = tmap[ti];
  if (e < 0) return;
  const int rowb = tmap[MAXT + ti];
  const int cnt = cnt_off[e];
  const int off = cnt_off[8 + e];
  const int colb = blockIdx.x;
  const int t = (int)threadIdx.x, w = t >> 6, l = t & 63;
  const int cs = (l & 7) ^ (l >> 3);         // pre-swizzled source chunk col
  const bf16* gA[4];
  const bf16* gB[4];
  #pragma unroll
  for (int it = 0; it < 4; ++it) {
    int rt = (it * 4 + w) * 8 + (l >> 3);
    int r = rowb * BM + rt;
    int rc = r < cnt ? r : cnt - 1;
    long arow = GATHER ? (long)row_ids[off + rc] : (long)(off + rc);
    gA[it] = Ab + arow * (long)KDIM + cs * 8;
  }
  #pragma unroll
  for (int it = 0; it < 4; ++it) {
    int rt = (it * 4 + w) * 8 + (l >> 3);
    gB[it] = Wt + ((size_t)e * N + (size_t)colb * BN + rt) * KDIM + cs * 8;
  }
  v4f acc[4][4] = {};
  const int wm = w >> 1, wn = w & 1;

#define STAGE(b, k0) do {                                                   \
    _Pragma("unroll")                                                       \
    for (int it = 0; it < 4; ++it)                                          \
      gl_lds16(gA[it] + (k0), &lds[b][0][(it * 4 + w) * 512]);              \
    _Pragma("unroll")                                                       \
    for (int it = 0; it < 4; ++it)                                          \
      gl_lds16(gB[it] + (k0), &lds[b][1][(it * 4 + w) * 512]);              \
  } while (0)

#define COMPUTE(b) do {                                                     \
    _Pragma("unroll")                                                       \
    for (int kk = 0; kk < 2; ++kk) {                                        \
      v8s af[4], bfr[4];                                                    \
      _Pragma("unroll")                                                     \
      for (int fm = 0; fm < 4; ++fm) {                                      \
        int row = wm * 64 + fm * 16 + (l & 15);                             \
        int cg = kk * 4 + (l >> 4);                                         \
        af[fm] = *(const v8s*)(&lds[b][0][0] + row * BK + ((cg ^ (row & 7)) << 3)); \
      }                                                                     \
      _Pragma("unroll")                                                     \
      for (int fn = 0; fn < 4; ++fn) {                                      \
        int row = wn * 64 + fn * 16 + (l & 15);                             \
        int cg = kk * 4 + (l >> 4);                                         \
        bfr[fn] = *(const v8s*)(&lds[b][1][0] + row * BK + ((cg ^ (row & 7)) << 3)); \
      }                                                                     \
      _Pragma("unroll")                                                     \
      for (int fm = 0; fm < 4; ++fm)                                        \
        _Pragma("unroll")                                                   \
        for (int fn = 0; fn < 4; ++fn)                                      \
          acc[fm][fn] = __builtin_amdgcn_mfma_f32_16x16x32_bf16(af[fm], bfr[fn], acc[fm][fn], 0, 0, 0); \
    }                                                                       \
  } while (0)

// one pipeline step: stage tile (kn) into buf (j+3)&3, wait own loads for buf j,
// barrier (data ready), compute, barrier (WAR: buf (j+3)&3 free to overwrite next step)
#define PIPE_STEP(j, kn, VMS) do {                                          \
    if ((kn) < NK) STAGE((j + 3) & 3, (kn) * BK);                           \
    asm volatile("s_waitcnt " VMS ::: "memory");                            \
    __builtin_amdgcn_sched_barrier(0);                                      \
    __builtin_amdgcn_s_barrier();                                           \
    __builtin_amdgcn_sched_barrier(0);                                      \
    COMPUTE(j);                                                             \
    __builtin_amdgcn_s_barrier();                                           \
    __builtin_amdgcn_sched_barrier(0);                                      \
  } while (0)

  STAGE(0, 0); STAGE(1, BK); STAGE(2, 2 * BK);   // depth-3 prologue (24 loads/wave)
  #pragma unroll 1
  for (int i4 = 0; i4 < NK - 4; i4 += 4) {
    PIPE_STEP(0, i4 + 3, "vmcnt(24)");
    PIPE_STEP(1, i4 + 4, "vmcnt(24)");
    PIPE_STEP(2, i4 + 5, "vmcnt(24)");
    PIPE_STEP(3, i4 + 6, "vmcnt(24)");
  }
  PIPE_STEP(0, NK - 1, "vmcnt(24)");
  PIPE_STEP(1, NK,     "vmcnt(16)");
  PIPE_STEP(2, NK + 1, "vmcnt(8)");
  PIPE_STEP(3, NK + 2, "vmcnt(0)");
#undef STAGE
#undef COMPUTE
#undef PIPE_STEP

  // ---- epilogue: per-wave LDS transpose -> bias(+gelu) -> coalesced 16B stores
  float* eps = (float*)(&lds[0][0][0]) + w * (16 * 68);   // 16 rows x 68 f32, wave-private
  const float* bp = bias + (size_t)e * N + (size_t)colb * BN + wn * 64 + (l & 7) * 8;
  float bv[8];
  #pragma unroll
  for (int jj = 0; jj < 8; ++jj) bv[jj] = bp[jj];
  #pragma unroll
  for (int fm = 0; fm < 4; ++fm) {
    #pragma unroll
    for (int fn = 0; fn < 4; ++fn)
      #pragma unroll
      for (int q = 0; q < 4; ++q)
        eps[((l >> 4) * 4 + q) * 68 + fn * 16 + (l & 15)] = acc[fm][fn][q];
    #pragma unroll
    for (int half = 0; half < 2; ++half) {
      int row = (l >> 3) + 8 * half;
      int r = rowb * BM + wm * 64 + fm * 16 + row;
      if (r < cnt) {
        const float* rp = eps + row * 68 + (l & 7) * 8;
        union { bf16 h[8]; uint4 u; } pk;
        #pragma unroll
        for (int jj = 0; jj < 8; ++jj) {
          float v = rp[jj] + bv[jj];
          if (GELU) {
            float u = 0.7978845608028654f * (v + 0.044715f * v * v * v);
            float th = 1.f - 2.f / (__expf(2.f * u) + 1.f);   // tanh(u)
            v = 0.5f * v * (1.f + th);
          }
          pk.h[jj] = __float2bfloat16(v);
        }
        *(uint4*)(Outb + (size_t)(off + r) * N + (size_t)colb * BN + wn * 64 + (l & 7) * 8) = pk.u;
      }
    }
  }
}

// ---------------------------------------------------------------- combine
__global__ void combine_kernel(const bf16* __restrict__ z, const float* __restrict__ gates,
                               const int* __restrict__ pos, float* __restrict__ y) {
  int gt = blockIdx.x * 256 + threadIdx.x;
  int tok = gt >> 6, l = gt & 63;
  if (tok >= B_TOK) return;
  const bf16* z1 = z + (size_t)pos[2 * tok] * D_OUT;
  const bf16* z2 = z + (size_t)pos[2 * tok + 1] * D_OUT;
  float g1 = gates[2 * tok], g2 = gates[2 * tok + 1];
  float a[12], b[12];
  float m1 = -1e30f, m2 = -1e30f;
  #pragma unroll
  for (int i = 0; i < 12; ++i) {
    a[i] = __bfloat162float(z1[l + 64 * i]);
    b[i] = __bfloat162float(z2[l + 64 * i]);
    m1 = fmaxf(m1, a[i]); m2 = fmaxf(m2, b[i]);
  }
  #pragma unroll
  for (int d = 1; d < 64; d <<= 1) {
    m1 = fmaxf(m1, __shfl_xor(m1, d));
    m2 = fmaxf(m2, __shfl_xor(m2, d));
  }
  float s1 = 0.f, s2 = 0.f;
  #pragma unroll
  for (int i = 0; i < 12; ++i) { s1 += __expf(a[i] - m1); s2 += __expf(b[i] - m2); }
  #pragma unroll
  for (int d = 1; d < 64; d <<= 1) { s1 += __shfl_xor(s1, d); s2 += __shfl_xor(s2, d); }
  float c1 = g1 / s1, c2 = g2 / s2;
  #pragma unroll
  for (int i = 0; i < 12; ++i) {
    float cmb = c1 * __expf(a[i] - m1) + c2 * __expf(b[i] - m2);
    y[(size_t)tok * D_OUT + l + 64 * i] = logf(cmb == 0.f ? 2.2204460492503131e-16f : cmb);
  }
}

// ---------------------------------------------------------------- launch
extern "C" void kernel_launch(void* const* d_in, const int* in_sizes, int n_in,
                              void* d_out, int out_size, void* d_ws, size_t ws_size,
                              hipStream_t stream) {
  const float* x  = (const float*)d_in[0];
  const float* wg = (const float*)d_in[1];
  const float* W1 = (const float*)d_in[2];
  const float* b1 = (const float*)d_in[3];
  const float* W2 = (const float*)d_in[4];
  const float* b2 = (const float*)d_in[5];
  float* out = (float*)d_out;

  char* ws = (char*)d_ws;
  int*   cnt_off = (int*)(ws + 0);                // [16]: counts then offsets
  float* gates   = (float*)(ws + 256);            // 4096*2 f32
  int*   tidx    = (int*)(ws + 256 + 32768);
  int*   pos     = (int*)(ws + 256 + 65536);
  int*   row_ids = (int*)(ws + 256 + 98304);
  int*   tmap    = (int*)(ws + 256 + 131072);     // [2*MAXT]
  const size_t base = 262144;
  bf16* x_bf = (bf16*)(ws + base);                        //  6,291,456 B
  bf16* W1t  = (bf16*)(ws + base + 6291456);              // 25,165,824 B
  bf16* W2t  = (bf16*)(ws + base + 31457280);             // 25,165,824 B
  bf16* h_bf = (bf16*)(ws + base + 56623104);             // 33,554,432 B
  bf16* z_bf = (bf16*)(ws + base);                        // aliases x_bf/W1t (dead by GEMM2)

  transpose_cvt<<<dim3(D_H / 64,  D_IN / 64, E_EXP), 256, 0, stream>>>(W1, W1t, D_IN, D_H);
  transpose_cvt<<<dim3(D_OUT / 64, D_H / 64, E_EXP), 256, 0, stream>>>(W2, W2t, D_H, D_OUT);
  gate_cvt_kernel<<<dim3(1024), 256, 0, stream>>>(x, wg, x_bf, gates, tidx);
  finalize_kernel<<<dim3(1), 256, 0, stream>>>(tidx, gates, cnt_off, row_ids, pos, tmap,
                                               out + (size_t)B_TOK * D_OUT);
  gemm_mlp<D_IN, true,  true ><<<dim3(D_H / 128,  MAXT), 256, 0, stream>>>(
      x_bf, W1t, b1, h_bf, row_ids, cnt_off, tmap, D_H);
  gemm_mlp<D_H,  false, false><<<dim3(D_OUT / 128, MAXT), 256, 0, stream>>>(
      h_bf, W2t, b2, z_bf, row_ids, cnt_off, tmap, D_OUT);
  combine_kernel<<<dim3(1024), 256, 0, stream>>>(z_bf, gates, pos, out);
}

// Round 5
// 170.664 us; speedup vs baseline: 1.9940x; 1.0392x over previous
//
#include <hip/hip_runtime.h>
#include <hip/hip_bf16.h>
#include <math.h>

typedef __hip_bfloat16 bf16;
typedef short v8s __attribute__((ext_vector_type(8)));
typedef float v4f __attribute__((ext_vector_type(4)));

#define B_TOK 4096
#define E_EXP 8
#define D_IN  768
#define D_H   2048
#define D_OUT 768
#define MAXTA 40      // max M-tiles of 256 (32 + 7 skew, padded)
#define MAXTB 72      // max M-tiles of 128 (64 + 7 skew, padded)

// ---------------------------------------------------------------- helpers
__device__ __forceinline__ void gl_lds16(const bf16* g, bf16* l) {
  __builtin_amdgcn_global_load_lds(
      (const __attribute__((address_space(1))) unsigned int*)g,
      (__attribute__((address_space(3))) unsigned int*)l, 16, 0, 0);
}

// ---------------------------------------------- fused x->bf16 + gating (no atomics)
__global__ void gate_cvt_kernel(const float* __restrict__ x, const float* __restrict__ wg,
                                bf16* __restrict__ xb,
                                float* __restrict__ gates, int* __restrict__ tidx) {
  int gt = blockIdx.x * 256 + threadIdx.x;
  int tok = gt >> 6, l = gt & 63;
  const float* xr = x + (size_t)tok * D_IN;
  bf16* xbr = xb + (size_t)tok * D_IN;
  float acc[8] = {0.f,0.f,0.f,0.f,0.f,0.f,0.f,0.f};
  #pragma unroll
  for (int i = 0; i < 3; ++i) {
    int k0 = i * 256 + l * 4;
    float4 v = *(const float4*)(xr + k0);
    union { bf16 h[4]; uint2 u; } pk;
    pk.h[0] = __float2bfloat16(v.x); pk.h[1] = __float2bfloat16(v.y);
    pk.h[2] = __float2bfloat16(v.z); pk.h[3] = __float2bfloat16(v.w);
    *(uint2*)(xbr + k0) = pk.u;
    float xv[4] = {v.x, v.y, v.z, v.w};
    #pragma unroll
    for (int j = 0; j < 4; ++j) {
      const float* wr = wg + (size_t)(k0 + j) * 8;
      float4 w0 = *(const float4*)wr;
      float4 w1 = *(const float4*)(wr + 4);
      acc[0] += xv[j] * w0.x; acc[1] += xv[j] * w0.y;
      acc[2] += xv[j] * w0.z; acc[3] += xv[j] * w0.w;
      acc[4] += xv[j] * w1.x; acc[5] += xv[j] * w1.y;
      acc[6] += xv[j] * w1.z; acc[7] += xv[j] * w1.w;
    }
  }
  #pragma unroll
  for (int d = 1; d < 64; d <<= 1)
    #pragma unroll
    for (int e = 0; e < 8; ++e) acc[e] += __shfl_xor(acc[e], d);
  if (l == 0) {
    int i1 = 0; float v1 = acc[0];
    #pragma unroll
    for (int e = 1; e < 8; ++e) if (acc[e] > v1) { v1 = acc[e]; i1 = e; }
    int i2 = -1; float v2 = -1e30f;
    #pragma unroll
    for (int e = 0; e < 8; ++e) if (e != i1 && acc[e] > v2) { v2 = acc[e]; i2 = e; }
    float ex = __expf(v2 - v1);
    float g1 = 1.f / (1.f + ex), g2 = ex / (1.f + ex);
    gates[2 * tok] = g1; gates[2 * tok + 1] = g2;
    tidx[2 * tok] = i1;  tidx[2 * tok + 1] = i2;
  }
}

// ---------------------------------------------- single-block: histogram + scan +
// slot assignment + counts/offsets + two tile maps + aux loss.  256 threads.
__global__ void finalize_kernel(const int* __restrict__ tidx, const float* __restrict__ gates,
                                int* __restrict__ cnt_off, int* __restrict__ row_ids,
                                int* __restrict__ pos, int* __restrict__ tmapA,
                                int* __restrict__ tmapB, float* __restrict__ loss_out) {
  __shared__ int   hcnt[256][9];
  __shared__ float himp[256][9];
  __shared__ int   tot[8], off[8];
  __shared__ float itot[8];
  int t = threadIdx.x;
  #pragma unroll
  for (int e = 0; e < 8; ++e) { hcnt[t][e] = 0; himp[t][e] = 0.f; }
  __syncthreads();
  for (int i = 0; i < 32; ++i) {
    int idx = t * 32 + i;
    int e = tidx[idx];
    hcnt[t][e] += 1;
    himp[t][e] += gates[idx];
  }
  __syncthreads();
  if (t < 8) {
    int run = 0; float s = 0.f;
    for (int j = 0; j < 256; ++j) {
      int c = hcnt[j][t];
      hcnt[j][t] = run;
      run += c;
      s += himp[j][t];
    }
    tot[t] = run; itot[t] = s;
  }
  __syncthreads();
  if (t == 0) {
    int o = 0;
    float mi = 0.f, ml = 0.f;
    for (int e = 0; e < 8; ++e) {
      off[e] = o; o += tot[e];
      cnt_off[e] = tot[e]; cnt_off[8 + e] = off[e];
      mi += itot[e]; ml += (float)tot[e];
    }
    mi *= 0.125f; ml *= 0.125f;
    float vi = 0.f, vl = 0.f;
    for (int e = 0; e < 8; ++e) {
      float d = itot[e] - mi;        vi += d * d;
      float d2 = (float)tot[e] - ml; vl += d2 * d2;
    }
    vi /= 7.f; vl /= 7.f;
    *loss_out = 0.01f * (vi / (mi * mi + 1e-10f) + vl / (ml * ml + 1e-10f));
    int nt = 0;
    for (int e = 0; e < 8; ++e)
      for (int tt = 0; tt < (tot[e] + 255) >> 8; ++tt) {
        tmapA[nt] = e; tmapA[MAXTA + nt] = tt; ++nt;
      }
    for (; nt < MAXTA; ++nt) tmapA[nt] = -1;
    nt = 0;
    for (int e = 0; e < 8; ++e)
      for (int tt = 0; tt < (tot[e] + 127) >> 7; ++tt) {
        tmapB[nt] = e; tmapB[MAXTB + nt] = tt; ++nt;
      }
    for (; nt < MAXTB; ++nt) tmapB[nt] = -1;
  }
  __syncthreads();
  for (int i = 0; i < 32; ++i) {
    int idx = t * 32 + i;
    int e = tidx[idx];
    int slot = off[e] + hcnt[t][e];
    hcnt[t][e] += 1;
    row_ids[slot] = idx >> 1;
    pos[idx] = slot;
  }
}

// ---------------------------------------------- W [E][K][N] f32 -> Wt [E][N][K] bf16
__global__ void transpose_cvt(const float* __restrict__ W, bf16* __restrict__ Wt,
                              int K, int N) {
  __shared__ bf16 tile[64][72];
  int e = blockIdx.z;
  int k0 = blockIdx.y * 64, n0 = blockIdx.x * 64;
  const float* Wp = W + (size_t)e * K * N;
  bf16* Wtp = Wt + (size_t)e * N * K;
  int t = threadIdx.x;
  int cr = t >> 4;
  int cc = (t & 15) * 4;
  #pragma unroll
  for (int p = 0; p < 4; ++p) {
    int kr = cr + p * 16;
    float4 v = *(const float4*)(Wp + (size_t)(k0 + kr) * N + n0 + cc);
    tile[cc + 0][kr] = __float2bfloat16(v.x);
    tile[cc + 1][kr] = __float2bfloat16(v.y);
    tile[cc + 2][kr] = __float2bfloat16(v.z);
    tile[cc + 3][kr] = __float2bfloat16(v.w);
  }
  __syncthreads();
  #pragma unroll
  for (int p = 0; p < 2; ++p) {
    int o = p * 256 + t;
    int n = o >> 3, k8 = (o & 7) * 8;
    v8s val = *(const v8s*)&tile[n][k8];
    *(v8s*)(Wtp + (size_t)(n0 + n) * K + k0 + k8) = val;
  }
}

// ---------------------------------------------------------------- grouped GEMM
// 256-wide-tile 8-wave structure: BN=256, BM=256 (GEMM1) / 128 (GEMM2), BK=64,
// 512 threads as 2M x 4N waves, 2-buffer counted-vmcnt pipeline (never drains
// to 0 in steady state), XOR-(row&7) chunk swizzle both sides, raw s_barrier.
template<int KDIM, int BM, bool GATHER, bool GELU>
__global__ __launch_bounds__(512, 2)
void gemm_mlp(const bf16* __restrict__ Ab, const bf16* __restrict__ Wt,
              const float* __restrict__ bias, bf16* __restrict__ Outb,
              const int* __restrict__ row_ids, const int* __restrict__ cnt_off,
              const int* __restrict__ tmap, const int maxt, const int N) {
  constexpr int BK = 64, BN = 256;
  constexpr int NK = KDIM / BK;
  constexpr int ITA = BM / 64;          // A-stage gl_lds16 per thread per K-tile
  constexpr int FM  = BM / 32;          // 16-row frags per wave in M
  static_assert(NK % 2 == 0 && NK >= 4, "NK even, >=4");
  __shared__ __align__(16) bf16 lds[2][(BM + BN) * BK];
  const int ti = blockIdx.y;
  const int e = tmap[ti];
  if (e < 0) return;
  const int rowb = tmap[maxt + ti];
  const int cnt = cnt_off[e];
  const int off = cnt_off[8 + e];
  const int colb = blockIdx.x;
  const int t = (int)threadIdx.x, w = t >> 6, l = t & 63;
  const int cs = (l & 7) ^ (l >> 3);    // pre-swizzled source chunk col
  const bf16* gA[ITA];
  const bf16* gB[4];
  #pragma unroll
  for (int it = 0; it < ITA; ++it) {
    int rt = (it * 8 + w) * 8 + (l >> 3);
    int r = rowb * BM + rt;
    int rc = r < cnt ? r : cnt - 1;
    long arow = GATHER ? (long)row_ids[off + rc] : (long)(off + rc);
    gA[it] = Ab + arow * (long)KDIM + cs * 8;
  }
  #pragma unroll
  for (int it = 0; it < 4; ++it) {
    int rt = (it * 8 + w) * 8 + (l >> 3);
    gB[it] = Wt + ((size_t)e * N + (size_t)colb * BN + rt) * KDIM + cs * 8;
  }
  v4f acc[FM][4] = {};
  const int wm = w >> 2, wn = w & 3;    // 2 x 4 wave grid

#define STAGE(b, k0) do {                                                   \
    _Pragma("unroll")                                                       \
    for (int it = 0; it < ITA; ++it)                                        \
      gl_lds16(gA[it] + (k0), &lds[b][(it * 8 + w) * 512]);                 \
    _Pragma("unroll")                                                       \
    for (int it = 0; it < 4; ++it)                                          \
      gl_lds16(gB[it] + (k0), &lds[b][BM * BK + (it * 8 + w) * 512]);       \
  } while (0)

#define COMPUTE(b) do {                                                     \
    __builtin_amdgcn_s_setprio(1);                                          \
    _Pragma("unroll")                                                       \
    for (int kk = 0; kk < 2; ++kk) {                                        \
      v8s af[FM], bfr[4];                                                   \
      _Pragma("unroll")                                                     \
      for (int fm = 0; fm < FM; ++fm) {                                     \
        int row = wm * (BM / 2) + fm * 16 + (l & 15);                       \
        int cg = kk * 4 + (l >> 4);                                         \
        af[fm] = *(const v8s*)(&lds[b][0] + row * BK + ((cg ^ (row & 7)) << 3)); \
      }                                                                     \
      _Pragma("unroll")                                                     \
      for (int fn = 0; fn < 4; ++fn) {                                      \
        int row = wn * 64 + fn * 16 + (l & 15);                             \
        int cg = kk * 4 + (l >> 4);                                         \
        bfr[fn] = *(const v8s*)(&lds[b][BM * BK] + row * BK + ((cg ^ (row & 7)) << 3)); \
      }                                                                     \
      _Pragma("unroll")                                                     \
      for (int fm = 0; fm < FM; ++fm)                                       \
        _Pragma("unroll")                                                   \
        for (int fn = 0; fn < 4; ++fn)                                      \
          acc[fm][fn] = __builtin_amdgcn_mfma_f32_16x16x32_bf16(af[fm], bfr[fn], acc[fm][fn], 0, 0, 0); \
    }                                                                       \
    __builtin_amdgcn_s_setprio(0);                                          \
  } while (0)

#define SB   __builtin_amdgcn_sched_barrier(0)
#define BARR __builtin_amdgcn_s_barrier()
#define WAITLPT do { if (ITA == 4) asm volatile("s_waitcnt vmcnt(8)" ::: "memory"); \
                     else          asm volatile("s_waitcnt vmcnt(6)" ::: "memory"); } while (0)
#define WAITZ  asm volatile("s_waitcnt vmcnt(0)" ::: "memory")

  STAGE(0, 0);
  #pragma unroll 1
  for (int ks = 0; ks < NK - 2; ks += 2) {
    STAGE(1, (ks + 1) * BK);
    WAITLPT; SB; BARR; SB;
    COMPUTE(0);
    BARR; SB;
    STAGE(0, (ks + 2) * BK);
    WAITLPT; SB; BARR; SB;
    COMPUTE(1);
    BARR; SB;
  }
  STAGE(1, (NK - 1) * BK);
  WAITLPT; SB; BARR; SB;
  COMPUTE(0);
  WAITZ; SB; BARR; SB;
  COMPUTE(1);
#undef STAGE
#undef COMPUTE
#undef WAITLPT
#undef WAITZ

  // ---- epilogue: per-wave LDS transpose -> bias(+gelu) -> coalesced 16B stores
  float* eps = (float*)(&lds[0][0]) + w * (16 * 68);   // 16 rows x 68 f32, wave-private
  const float* bp = bias + (size_t)e * N + (size_t)colb * BN + wn * 64 + (l & 7) * 8;
  float bv[8];
  #pragma unroll
  for (int jj = 0; jj < 8; ++jj) bv[jj] = bp[jj];
  #pragma unroll
  for (int fm = 0; fm < FM; ++fm) {
    #pragma unroll
    for (int fn = 0; fn < 4; ++fn)
      #pragma unroll
      for (int q = 0; q < 4; ++q)
        eps[((l >> 4) * 4 + q) * 68 + fn * 16 + (l & 15)] = acc[fm][fn][q];
    #pragma unroll
    for (int half = 0; half < 2; ++half) {
      int row = (l >> 3) + 8 * half;
      int r = rowb * BM + wm * (BM / 2) + fm * 16 + row;
      if (r < cnt) {
        const float* rp = eps + row * 68 + (l & 7) * 8;
        union { bf16 h[8]; uint4 u; } pk;
        #pragma unroll
        for (int jj = 0; jj < 8; ++jj) {
          float v = rp[jj] + bv[jj];
          if (GELU) {
            float u = 0.7978845608028654f * (v + 0.044715f * v * v * v);
            float th = 1.f - 2.f / (__expf(2.f * u) + 1.f);   // tanh(u)
            v = 0.5f * v * (1.f + th);
          }
          pk.h[jj] = __float2bfloat16(v);
        }
        *(uint4*)(Outb + (size_t)(off + r) * N + (size_t)colb * BN + wn * 64 + (l & 7) * 8) = pk.u;
      }
    }
  }
#undef SB
#undef BARR
}

// ---------------------------------------------------------------- combine
__global__ void combine_kernel(const bf16* __restrict__ z, const float* __restrict__ gates,
                               const int* __restrict__ pos, float* __restrict__ y) {
  int gt = blockIdx.x * 256 + threadIdx.x;
  int tok = gt >> 6, l = gt & 63;
  if (tok >= B_TOK) return;
  const bf16* z1 = z + (size_t)pos[2 * tok] * D_OUT;
  const bf16* z2 = z + (size_t)pos[2 * tok + 1] * D_OUT;
  float g1 = gates[2 * tok], g2 = gates[2 * tok + 1];
  float a[12], b[12];
  float m1 = -1e30f, m2 = -1e30f;
  #pragma unroll
  for (int i = 0; i < 12; ++i) {
    a[i] = __bfloat162float(z1[l + 64 * i]);
    b[i] = __bfloat162float(z2[l + 64 * i]);
    m1 = fmaxf(m1, a[i]); m2 = fmaxf(m2, b[i]);
  }
  #pragma unroll
  for (int d = 1; d < 64; d <<= 1) {
    m1 = fmaxf(m1, __shfl_xor(m1, d));
    m2 = fmaxf(m2, __shfl_xor(m2, d));
  }
  float s1 = 0.f, s2 = 0.f;
  #pragma unroll
  for (int i = 0; i < 12; ++i) { s1 += __expf(a[i] - m1); s2 += __expf(b[i] - m2); }
  #pragma unroll
  for (int d = 1; d < 64; d <<= 1) { s1 += __shfl_xor(s1, d); s2 += __shfl_xor(s2, d); }
  float c1 = g1 / s1, c2 = g2 / s2;
  #pragma unroll
  for (int i = 0; i < 12; ++i) {
    float cmb = c1 * __expf(a[i] - m1) + c2 * __expf(b[i] - m2);
    y[(size_t)tok * D_OUT + l + 64 * i] = logf(cmb == 0.f ? 2.2204460492503131e-16f : cmb);
  }
}

// ---------------------------------------------------------------- launch
extern "C" void kernel_launch(void* const* d_in, const int* in_sizes, int n_in,
                              void* d_out, int out_size, void* d_ws, size_t ws_size,
                              hipStream_t stream) {
  const float* x  = (const float*)d_in[0];
  const float* wg = (const float*)d_in[1];
  const float* W1 = (const float*)d_in[2];
  const float* b1 = (const float*)d_in[3];
  const float* W2 = (const float*)d_in[4];
  const float* b2 = (const float*)d_in[5];
  float* out = (float*)d_out;

  char* ws = (char*)d_ws;
  int*   cnt_off = (int*)(ws + 0);                // [16]: counts then offsets
  float* gates   = (float*)(ws + 256);            // 4096*2 f32
  int*   tidx    = (int*)(ws + 256 + 32768);
  int*   pos     = (int*)(ws + 256 + 65536);
  int*   row_ids = (int*)(ws + 256 + 98304);
  int*   tmapA   = (int*)(ws + 256 + 131072);     // [2*MAXTA]
  int*   tmapB   = tmapA + 2 * MAXTA;             // [2*MAXTB]
  const size_t base = 262144;
  bf16* x_bf = (bf16*)(ws + base);                        //  6,291,456 B
  bf16* W1t  = (bf16*)(ws + base + 6291456);              // 25,165,824 B
  bf16* W2t  = (bf16*)(ws + base + 31457280);             // 25,165,824 B
  bf16* h_bf = (bf16*)(ws + base + 56623104);             // 33,554,432 B
  bf16* z_bf = (bf16*)(ws + base);                        // aliases x_bf/W1t (dead by GEMM2)

  transpose_cvt<<<dim3(D_H / 64,  D_IN / 64, E_EXP), 256, 0, stream>>>(W1, W1t, D_IN, D_H);
  transpose_cvt<<<dim3(D_OUT / 64, D_H / 64, E_EXP), 256, 0, stream>>>(W2, W2t, D_H, D_OUT);
  gate_cvt_kernel<<<dim3(1024), 256, 0, stream>>>(x, wg, x_bf, gates, tidx);
  finalize_kernel<<<dim3(1), 256, 0, stream>>>(tidx, gates, cnt_off, row_ids, pos,
                                               tmapA, tmapB, out + (size_t)B_TOK * D_OUT);
  gemm_mlp<D_IN, 256, true,  true ><<<dim3(D_H / 256,  MAXTA), 512, 0, stream>>>(
      x_bf, W1t, b1, h_bf, row_ids, cnt_off, tmapA, MAXTA, D_H);
  gemm_mlp<D_H,  128, false, false><<<dim3(D_OUT / 256, MAXTB), 512, 0, stream>>>(
      h_bf, W2t, b2, z_bf, row_ids, cnt_off, tmapB, MAXTB, D_OUT);
  combine_kernel<<<dim3(1024), 256, 0, stream>>>(z_bf, gates, pos, out);
}

// Round 6
// 162.493 us; speedup vs baseline: 2.0942x; 1.0503x over previous
//
#include <hip/hip_runtime.h>
#include <hip/hip_bf16.h>
#include <math.h>

typedef __hip_bfloat16 bf16;
typedef short v8s __attribute__((ext_vector_type(8)));
typedef float v4f __attribute__((ext_vector_type(4)));

#define B_TOK 4096
#define E_EXP 8
#define D_IN  768
#define D_H   2048
#define D_OUT 768
#define MAXT  72      // max M-tiles of 128 over all experts (64 + 7 skew, padded)

// ---------------------------------------------------------------- helpers
__device__ __forceinline__ void gl_lds16(const bf16* g, bf16* l) {
  __builtin_amdgcn_global_load_lds(
      (const __attribute__((address_space(1))) unsigned int*)g,
      (__attribute__((address_space(3))) unsigned int*)l, 16, 0, 0);
}

// ---------------------------------------------- fused x->bf16 + gating (no atomics)
__global__ void gate_cvt_kernel(const float* __restrict__ x, const float* __restrict__ wg,
                                bf16* __restrict__ xb,
                                float* __restrict__ gates, int* __restrict__ tidx) {
  int gt = blockIdx.x * 256 + threadIdx.x;
  int tok = gt >> 6, l = gt & 63;
  const float* xr = x + (size_t)tok * D_IN;
  bf16* xbr = xb + (size_t)tok * D_IN;
  float acc[8] = {0.f,0.f,0.f,0.f,0.f,0.f,0.f,0.f};
  #pragma unroll
  for (int i = 0; i < 3; ++i) {
    int k0 = i * 256 + l * 4;
    float4 v = *(const float4*)(xr + k0);
    union { bf16 h[4]; uint2 u; } pk;
    pk.h[0] = __float2bfloat16(v.x); pk.h[1] = __float2bfloat16(v.y);
    pk.h[2] = __float2bfloat16(v.z); pk.h[3] = __float2bfloat16(v.w);
    *(uint2*)(xbr + k0) = pk.u;
    float xv[4] = {v.x, v.y, v.z, v.w};
    #pragma unroll
    for (int j = 0; j < 4; ++j) {
      const float* wr = wg + (size_t)(k0 + j) * 8;
      float4 w0 = *(const float4*)wr;
      float4 w1 = *(const float4*)(wr + 4);
      acc[0] += xv[j] * w0.x; acc[1] += xv[j] * w0.y;
      acc[2] += xv[j] * w0.z; acc[3] += xv[j] * w0.w;
      acc[4] += xv[j] * w1.x; acc[5] += xv[j] * w1.y;
      acc[6] += xv[j] * w1.z; acc[7] += xv[j] * w1.w;
    }
  }
  #pragma unroll
  for (int d = 1; d < 64; d <<= 1)
    #pragma unroll
    for (int e = 0; e < 8; ++e) acc[e] += __shfl_xor(acc[e], d);
  if (l == 0) {
    int i1 = 0; float v1 = acc[0];
    #pragma unroll
    for (int e = 1; e < 8; ++e) if (acc[e] > v1) { v1 = acc[e]; i1 = e; }
    int i2 = -1; float v2 = -1e30f;
    #pragma unroll
    for (int e = 0; e < 8; ++e) if (e != i1 && acc[e] > v2) { v2 = acc[e]; i2 = e; }
    float ex = __expf(v2 - v1);
    float g1 = 1.f / (1.f + ex), g2 = ex / (1.f + ex);
    gates[2 * tok] = g1; gates[2 * tok + 1] = g2;
    tidx[2 * tok] = i1;  tidx[2 * tok + 1] = i2;
  }
}

// ---------------------------------------------- single-block: histogram + scan +
// slot assignment + counts/offsets + tile map + aux loss.  256 threads.
__global__ void finalize_kernel(const int* __restrict__ tidx, const float* __restrict__ gates,
                                int* __restrict__ cnt_off, int* __restrict__ row_ids,
                                int* __restrict__ pos, int* __restrict__ tmap,
                                float* __restrict__ loss_out) {
  __shared__ int   hcnt[256][9];
  __shared__ float himp[256][9];
  __shared__ int   tot[8], off[8];
  __shared__ float itot[8];
  int t = threadIdx.x;
  #pragma unroll
  for (int e = 0; e < 8; ++e) { hcnt[t][e] = 0; himp[t][e] = 0.f; }
  __syncthreads();
  for (int i = 0; i < 32; ++i) {
    int idx = t * 32 + i;
    int e = tidx[idx];
    hcnt[t][e] += 1;
    himp[t][e] += gates[idx];
  }
  __syncthreads();
  if (t < 8) {
    int run = 0; float s = 0.f;
    for (int j = 0; j < 256; ++j) {
      int c = hcnt[j][t];
      hcnt[j][t] = run;
      run += c;
      s += himp[j][t];
    }
    tot[t] = run; itot[t] = s;
  }
  __syncthreads();
  if (t == 0) {
    int o = 0;
    float mi = 0.f, ml = 0.f;
    for (int e = 0; e < 8; ++e) {
      off[e] = o; o += tot[e];
      cnt_off[e] = tot[e]; cnt_off[8 + e] = off[e];
      mi += itot[e]; ml += (float)tot[e];
    }
    mi *= 0.125f; ml *= 0.125f;
    float vi = 0.f, vl = 0.f;
    for (int e = 0; e < 8; ++e) {
      float d = itot[e] - mi;        vi += d * d;
      float d2 = (float)tot[e] - ml; vl += d2 * d2;
    }
    vi /= 7.f; vl /= 7.f;
    *loss_out = 0.01f * (vi / (mi * mi + 1e-10f) + vl / (ml * ml + 1e-10f));
    int nt = 0;
    for (int e = 0; e < 8; ++e)
      for (int tt = 0; tt < (tot[e] + 127) >> 7; ++tt) {
        tmap[nt] = e; tmap[MAXT + nt] = tt; ++nt;
      }
    for (; nt < MAXT; ++nt) tmap[nt] = -1;
  }
  __syncthreads();
  for (int i = 0; i < 32; ++i) {
    int idx = t * 32 + i;
    int e = tidx[idx];
    int slot = off[e] + hcnt[t][e];
    hcnt[t][e] += 1;
    row_ids[slot] = idx >> 1;
    pos[idx] = slot;
  }
}

// ---------------------------------------------- W [E][K][N] f32 -> Wt [E][N][K] bf16
__global__ void transpose_cvt(const float* __restrict__ W, bf16* __restrict__ Wt,
                              int K, int N) {
  __shared__ bf16 tile[64][72];
  int e = blockIdx.z;
  int k0 = blockIdx.y * 64, n0 = blockIdx.x * 64;
  const float* Wp = W + (size_t)e * K * N;
  bf16* Wtp = Wt + (size_t)e * N * K;
  int t = threadIdx.x;
  int cr = t >> 4;
  int cc = (t & 15) * 4;
  #pragma unroll
  for (int p = 0; p < 4; ++p) {
    int kr = cr + p * 16;
    float4 v = *(const float4*)(Wp + (size_t)(k0 + kr) * N + n0 + cc);
    tile[cc + 0][kr] = __float2bfloat16(v.x);
    tile[cc + 1][kr] = __float2bfloat16(v.y);
    tile[cc + 2][kr] = __float2bfloat16(v.z);
    tile[cc + 3][kr] = __float2bfloat16(v.w);
  }
  __syncthreads();
  #pragma unroll
  for (int p = 0; p < 2; ++p) {
    int o = p * 256 + t;
    int n = o >> 3, k8 = (o & 7) * 8;
    v8s val = *(const v8s*)&tile[n][k8];
    *(v8s*)(Wtp + (size_t)(n0 + n) * K + k0 + k8) = val;
  }
}

// ---------------------------------------------------------------- grouped GEMM
// 128x128 tile, 256 threads (2x2 waves), 2-buffer counted-vmcnt pipeline,
// 64 KiB LDS -> 2 blocks/CU co-resident (partner block hides vmcnt/barrier
// stalls).  XOR-(row&7) chunk swizzle both sides (verified R2-R4 math).
template<int KDIM, bool GATHER, bool GELU>
__global__ __launch_bounds__(256, 2)
void gemm_mlp(const bf16* __restrict__ Ab, const bf16* __restrict__ Wt,
              const float* __restrict__ bias, bf16* __restrict__ Outb,
              const int* __restrict__ row_ids, const int* __restrict__ cnt_off,
              const int* __restrict__ tmap, const int N) {
  constexpr int BK = 64, BM = 128, BN = 128;
  constexpr int NK = KDIM / BK;
  static_assert(NK % 2 == 0 && NK >= 4, "NK even, >=4");
  __shared__ __align__(16) bf16 lds[2][(BM + BN) * BK];   // 2 x 32 KiB
  const int ti = blockIdx.y;
  const int e = tmap[ti];
  if (e < 0) return;
  const int rowb = tmap[MAXT + ti];
  const int cnt = cnt_off[e];
  const int off = cnt_off[8 + e];
  const int colb = blockIdx.x;
  const int t = (int)threadIdx.x, w = t >> 6, l = t & 63;
  const int cs = (l & 7) ^ (l >> 3);    // pre-swizzled source chunk col
  const bf16* gA[4];
  const bf16* gB[4];
  #pragma unroll
  for (int it = 0; it < 4; ++it) {
    int rt = (it * 4 + w) * 8 + (l >> 3);
    int r = rowb * BM + rt;
    int rc = r < cnt ? r : cnt - 1;
    long arow = GATHER ? (long)row_ids[off + rc] : (long)(off + rc);
    gA[it] = Ab + arow * (long)KDIM + cs * 8;
  }
  #pragma unroll
  for (int it = 0; it < 4; ++it) {
    int rt = (it * 4 + w) * 8 + (l >> 3);
    gB[it] = Wt + ((size_t)e * N + (size_t)colb * BN + rt) * KDIM + cs * 8;
  }
  v4f acc[4][4] = {};
  const int wm = w >> 1, wn = w & 1;    // 2 x 2 wave grid

#define STAGE(b, k0) do {                                                   \
    _Pragma("unroll")                                                       \
    for (int it = 0; it < 4; ++it)                                          \
      gl_lds16(gA[it] + (k0), &lds[b][(it * 4 + w) * 512]);                 \
    _Pragma("unroll")                                                       \
    for (int it = 0; it < 4; ++it)                                          \
      gl_lds16(gB[it] + (k0), &lds[b][BM * BK + (it * 4 + w) * 512]);       \
  } while (0)

#define COMPUTE(b) do {                                                     \
    __builtin_amdgcn_s_setprio(1);                                          \
    _Pragma("unroll")                                                       \
    for (int kk = 0; kk < 2; ++kk) {                                        \
      v8s af[4], bfr[4];                                                    \
      _Pragma("unroll")                                                     \
      for (int fm = 0; fm < 4; ++fm) {                                      \
        int row = wm * 64 + fm * 16 + (l & 15);                             \
        int cg = kk * 4 + (l >> 4);                                         \
        af[fm] = *(const v8s*)(&lds[b][0] + row * BK + ((cg ^ (row & 7)) << 3)); \
      }                                                                     \
      _Pragma("unroll")                                                     \
      for (int fn = 0; fn < 4; ++fn) {                                      \
        int row = wn * 64 + fn * 16 + (l & 15);                             \
        int cg = kk * 4 + (l >> 4);                                         \
        bfr[fn] = *(const v8s*)(&lds[b][BM * BK] + row * BK + ((cg ^ (row & 7)) << 3)); \
      }                                                                     \
      _Pragma("unroll")                                                     \
      for (int fm = 0; fm < 4; ++fm)                                        \
        _Pragma("unroll")                                                   \
        for (int fn = 0; fn < 4; ++fn)                                      \
          acc[fm][fn] = __builtin_amdgcn_mfma_f32_16x16x32_bf16(af[fm], bfr[fn], acc[fm][fn], 0, 0, 0); \
    }                                                                       \
    __builtin_amdgcn_s_setprio(0);                                          \
  } while (0)

#define SB    __builtin_amdgcn_sched_barrier(0)
#define BARR  __builtin_amdgcn_s_barrier()
#define WAIT8 asm volatile("s_waitcnt vmcnt(8)" ::: "memory")
#define WAITZ asm volatile("s_waitcnt vmcnt(0)" ::: "memory")

  STAGE(0, 0);
  #pragma unroll 1
  for (int ks = 0; ks < NK - 2; ks += 2) {
    STAGE(1, (ks + 1) * BK);
    WAIT8; SB; BARR; SB;
    COMPUTE(0);
    BARR; SB;
    STAGE(0, (ks + 2) * BK);
    WAIT8; SB; BARR; SB;
    COMPUTE(1);
    BARR; SB;
  }
  STAGE(1, (NK - 1) * BK);
  WAIT8; SB; BARR; SB;
  COMPUTE(0);
  WAITZ; SB; BARR; SB;
  COMPUTE(1);
#undef STAGE
#undef COMPUTE
#undef WAIT8
#undef WAITZ

  // ---- epilogue: per-wave LDS transpose -> bias(+gelu) -> coalesced 16B stores
  float* eps = (float*)(&lds[0][0]) + w * (16 * 68);   // 16 rows x 68 f32, wave-private
  const float* bp = bias + (size_t)e * N + (size_t)colb * BN + wn * 64 + (l & 7) * 8;
  float bv[8];
  #pragma unroll
  for (int jj = 0; jj < 8; ++jj) bv[jj] = bp[jj];
  #pragma unroll
  for (int fm = 0; fm < 4; ++fm) {
    #pragma unroll
    for (int fn = 0; fn < 4; ++fn)
      #pragma unroll
      for (int q = 0; q < 4; ++q)
        eps[((l >> 4) * 4 + q) * 68 + fn * 16 + (l & 15)] = acc[fm][fn][q];
    #pragma unroll
    for (int half = 0; half < 2; ++half) {
      int row = (l >> 3) + 8 * half;
      int r = rowb * BM + wm * 64 + fm * 16 + row;
      if (r < cnt) {
        const float* rp = eps + row * 68 + (l & 7) * 8;
        union { bf16 h[8]; uint4 u; } pk;
        #pragma unroll
        for (int jj = 0; jj < 8; ++jj) {
          float v = rp[jj] + bv[jj];
          if (GELU) {
            float u = 0.7978845608028654f * (v + 0.044715f * v * v * v);
            float th = 1.f - 2.f / (__expf(2.f * u) + 1.f);   // tanh(u)
            v = 0.5f * v * (1.f + th);
          }
          pk.h[jj] = __float2bfloat16(v);
        }
        *(uint4*)(Outb + (size_t)(off + r) * N + (size_t)colb * BN + wn * 64 + (l & 7) * 8) = pk.u;
      }
    }
  }
#undef SB
#undef BARR
}

// ---------------------------------------------------------------- combine
__global__ void combine_kernel(const bf16* __restrict__ z, const float* __restrict__ gates,
                               const int* __restrict__ pos, float* __restrict__ y) {
  int gt = blockIdx.x * 256 + threadIdx.x;
  int tok = gt >> 6, l = gt & 63;
  if (tok >= B_TOK) return;
  const bf16* z1 = z + (size_t)pos[2 * tok] * D_OUT;
  const bf16* z2 = z + (size_t)pos[2 * tok + 1] * D_OUT;
  float g1 = gates[2 * tok], g2 = gates[2 * tok + 1];
  float a[12], b[12];
  float m1 = -1e30f, m2 = -1e30f;
  #pragma unroll
  for (int i = 0; i < 12; ++i) {
    a[i] = __bfloat162float(z1[l + 64 * i]);
    b[i] = __bfloat162float(z2[l + 64 * i]);
    m1 = fmaxf(m1, a[i]); m2 = fmaxf(m2, b[i]);
  }
  #pragma unroll
  for (int d = 1; d < 64; d <<= 1) {
    m1 = fmaxf(m1, __shfl_xor(m1, d));
    m2 = fmaxf(m2, __shfl_xor(m2, d));
  }
  float s1 = 0.f, s2 = 0.f;
  #pragma unroll
  for (int i = 0; i < 12; ++i) { s1 += __expf(a[i] - m1); s2 += __expf(b[i] - m2); }
  #pragma unroll
  for (int d = 1; d < 64; d <<= 1) { s1 += __shfl_xor(s1, d); s2 += __shfl_xor(s2, d); }
  float c1 = g1 / s1, c2 = g2 / s2;
  #pragma unroll
  for (int i = 0; i < 12; ++i) {
    float cmb = c1 * __expf(a[i] - m1) + c2 * __expf(b[i] - m2);
    y[(size_t)tok * D_OUT + l + 64 * i] = logf(cmb == 0.f ? 2.2204460492503131e-16f : cmb);
  }
}

// ---------------------------------------------------------------- launch
extern "C" void kernel_launch(void* const* d_in, const int* in_sizes, int n_in,
                              void* d_out, int out_size, void* d_ws, size_t ws_size,
                              hipStream_t stream) {
  const float* x  = (const float*)d_in[0];
  const float* wg = (const float*)d_in[1];
  const float* W1 = (const float*)d_in[2];
  const float* b1 = (const float*)d_in[3];
  const float* W2 = (const float*)d_in[4];
  const float* b2 = (const float*)d_in[5];
  float* out = (float*)d_out;

  char* ws = (char*)d_ws;
  int*   cnt_off = (int*)(ws + 0);                // [16]: counts then offsets
  float* gates   = (float*)(ws + 256);            // 4096*2 f32
  int*   tidx    = (int*)(ws + 256 + 32768);
  int*   pos     = (int*)(ws + 256 + 65536);
  int*   row_ids = (int*)(ws + 256 + 98304);
  int*   tmap    = (int*)(ws + 256 + 131072);     // [2*MAXT]
  const size_t base = 262144;
  bf16* x_bf = (bf16*)(ws + base);                        //  6,291,456 B
  bf16* W1t  = (bf16*)(ws + base + 6291456);              // 25,165,824 B
  bf16* W2t  = (bf16*)(ws + base + 31457280);             // 25,165,824 B
  bf16* h_bf = (bf16*)(ws + base + 56623104);             // 33,554,432 B
  bf16* z_bf = (bf16*)(ws + base);                        // aliases x_bf/W1t (dead by GEMM2)

  transpose_cvt<<<dim3(D_H / 64,  D_IN / 64, E_EXP), 256, 0, stream>>>(W1, W1t, D_IN, D_H);
  transpose_cvt<<<dim3(D_OUT / 64, D_H / 64, E_EXP), 256, 0, stream>>>(W2, W2t, D_H, D_OUT);
  gate_cvt_kernel<<<dim3(1024), 256, 0, stream>>>(x, wg, x_bf, gates, tidx);
  finalize_kernel<<<dim3(1), 256, 0, stream>>>(tidx, gates, cnt_off, row_ids, pos, tmap,
                                               out + (size_t)B_TOK * D_OUT);
  gemm_mlp<D_IN, true,  true ><<<dim3(D_H / 128,  MAXT), 256, 0, stream>>>(
      x_bf, W1t, b1, h_bf, row_ids, cnt_off, tmap, D_H);
  gemm_mlp<D_H,  false, false><<<dim3(D_OUT / 128, MAXT), 256, 0, stream>>>(
      h_bf, W2t, b2, z_bf, row_ids, cnt_off, tmap, D_OUT);
  combine_kernel<<<dim3(1024), 256, 0, stream>>>(z_bf, gates, pos, out);
}